// Round 12
// baseline (544.509 us; speedup 1.0000x reference)
//
#include <hip/hip_runtime.h>
#include <hip/hip_bf16.h>
#include <math.h>

// ---------------------------------------------------------------------------
// GraphMemoryNetwork — Round 12: R11 base; ffn phase-2 streams B direct from
// L2 (Bstage removed -> 64KB LDS, 2 blocks/CU, LDS traffic cut 3x).
// N=50000, E=640000, D_IN=256, D=128, H=8, DH=16, NC=47, L=3
// ---------------------------------------------------------------------------

typedef __bf16 bf16x8 __attribute__((ext_vector_type(8)));
typedef __bf16 bf16x4 __attribute__((ext_vector_type(4)));
typedef float  f32x4  __attribute__((ext_vector_type(4)));

#define MFMA16(a, b, c) __builtin_amdgcn_mfma_f32_16x16x32_bf16((a), (b), (c), 0, 0, 0)

// async 16B/lane global -> LDS (wave-uniform LDS base + lane*16)
__device__ __forceinline__ void ld_lds16(const __bf16* g, __bf16* l) {
    __builtin_amdgcn_global_load_lds(
        (__attribute__((address_space(1))) void*)g,
        (__attribute__((address_space(3))) void*)l, 16, 0, 0);
}

// ------------------------- CSR build ---------------------------------------

__global__ __launch_bounds__(256) void zero_ints(int* __restrict__ p, int n) {
    int i = blockIdx.x * 256 + threadIdx.x;
    if (i < n) p[i] = 0;
}

__global__ __launch_bounds__(256) void count_deg(const int* __restrict__ ei,
                                                 int* __restrict__ deg, int E) {
    int e = blockIdx.x * 256 + threadIdx.x;
    if (e < E) atomicAdd(&deg[ei[(size_t)E + e]], 1);   // dst = ei[1][e]
}

__global__ __launch_bounds__(256) void scan_part(const int* __restrict__ deg,
                                                 int* __restrict__ partials, int N) {
    int b = blockIdx.x, t = threadIdx.x, lane = t & 63, w = t >> 6;
    int base = b * 1024 + t * 4;
    int4 v = make_int4(0, 0, 0, 0);
    if (base + 3 < N) v = *(const int4*)&deg[base];
    else {
        if (base < N)     v.x = deg[base];
        if (base + 1 < N) v.y = deg[base + 1];
        if (base + 2 < N) v.z = deg[base + 2];
    }
    int s = v.x + v.y + v.z + v.w;
#pragma unroll
    for (int o = 1; o < 64; o <<= 1) s += __shfl_xor(s, o);
    __shared__ int ws[4];
    if (lane == 0) ws[w] = s;
    __syncthreads();
    if (t == 0) partials[b] = ws[0] + ws[1] + ws[2] + ws[3];
}

__global__ __launch_bounds__(64) void scan_mid(int* __restrict__ partials,
                                               int* __restrict__ row_ptr,
                                               int nb, int N) {
    int t = threadIdx.x;
    int v = (t < nb) ? partials[t] : 0;
    int incl = v;
#pragma unroll
    for (int o = 1; o < 64; o <<= 1) {
        int u = __shfl_up(incl, o);
        if (t >= o) incl += u;
    }
    if (t < nb) partials[t] = incl - v;
    if (t == nb - 1) row_ptr[N] = incl;
}

__global__ __launch_bounds__(256) void scan_final(const int* __restrict__ deg,
                                                  const int* __restrict__ partials,
                                                  int* __restrict__ row_ptr, int N) {
    int b = blockIdx.x, t = threadIdx.x, lane = t & 63, w = t >> 6;
    int base = b * 1024 + t * 4;
    int4 v = make_int4(0, 0, 0, 0);
    if (base + 3 < N) v = *(const int4*)&deg[base];
    else {
        if (base < N)     v.x = deg[base];
        if (base + 1 < N) v.y = deg[base + 1];
        if (base + 2 < N) v.z = deg[base + 2];
    }
    int c1 = v.x, c2 = c1 + v.y, c3 = c2 + v.z, c4 = c3 + v.w;
    int s = c4, incl = s;
#pragma unroll
    for (int o = 1; o < 64; o <<= 1) {
        int u = __shfl_up(incl, o);
        if (lane >= o) incl += u;
    }
    int texcl = incl - s;
    __shared__ int ws[4];
    if (lane == 63) ws[w] = incl;
    __syncthreads();
    int woff = 0;
    for (int i = 0; i < w; ++i) woff += ws[i];
    int off = partials[b] + woff + texcl;
    if (base < N)     row_ptr[base]     = off;
    if (base + 1 < N) row_ptr[base + 1] = off + c1;
    if (base + 2 < N) row_ptr[base + 2] = off + c2;
    if (base + 3 < N) row_ptr[base + 3] = off + c3;
}

__global__ __launch_bounds__(256) void scatter_edges(const int* __restrict__ ei,
                                                     const int* __restrict__ row_ptr,
                                                     int* __restrict__ cursor,
                                                     int* __restrict__ csr_src, int E) {
    int e = blockIdx.x * 256 + threadIdx.x;
    if (e < E) {
        int d = ei[(size_t)E + e];
        int pos = row_ptr[d] + atomicAdd(&cursor[d], 1);
        csr_src[pos] = ei[e];
    }
}

// ------------------------- batched weight transpose -------------------------

__global__ __launch_bounds__(256) void transpose_all(
    const float* __restrict__ emb_w, const float* __restrict__ f1w,
    const float* __restrict__ f2w, const float* __restrict__ f3w,
    const float* __restrict__ Wq, const float* __restrict__ Wk,
    const float* __restrict__ Wv, const float* __restrict__ Wo,
    __bf16* __restrict__ embT, __bf16* __restrict__ f1T,
    __bf16* __restrict__ f2T, __bf16* __restrict__ f3T,
    __bf16* __restrict__ qkvT, __bf16* __restrict__ woT) {
    __shared__ float tile[32][33];
    int t = blockIdx.x;
    const float* src; __bf16* dst; int K, Nin, Npad, nxt;
    if (t < 32)       { src = emb_w; dst = embT; K = 256; Nin = 128; Npad = 128; nxt = 4; }
    else if (t < 96)  { t -= 32;  src = f1w; dst = f1T; K = 128; Nin = 512; Npad = 512; nxt = 16; }
    else if (t < 352) { t -= 96;  src = f2w; dst = f2T; K = 512; Nin = 512; Npad = 512; nxt = 16; }
    else if (t < 384) { t -= 352; src = f3w; dst = f3T; K = 512; Nin = 47;  Npad = 48;  nxt = 2; }
    else {
        t -= 384;
        int mat = t >> 4; t &= 15;
        int l = mat >> 2, m = mat & 3;
        src = (m == 0 ? Wq : m == 1 ? Wk : m == 2 ? Wv : Wo) + (size_t)l * 16384;
        dst = (m < 3) ? qkvT + (size_t)l * 49152 + (size_t)m * 16384
                      : woT + (size_t)l * 16384;
        K = 128; Nin = 128; Npad = 128; nxt = 4;
    }
    int n0 = (t % nxt) * 32, k0 = (t / nxt) * 32;
    int tx = threadIdx.x & 31, ty = threadIdx.x >> 5;
#pragma unroll
    for (int i = 0; i < 32; i += 8) {
        int k = k0 + ty + i, n = n0 + tx;
        tile[ty + i][tx] = (k < K && n < Nin) ? src[(size_t)k * Nin + n] : 0.f;
    }
    __syncthreads();
#pragma unroll
    for (int i = 0; i < 32; i += 8) {
        int n = n0 + ty + i, k = k0 + tx;
        if (n < Npad && k < K) dst[(size_t)n * K + k] = (__bf16)tile[tx][ty + i];
    }
}

// ------------------------- block-tiled MFMA GEMM (async LDS staging) --------

template <int NK, int EPI>
__global__ __launch_bounds__(256) void gemm_tile(const __bf16* __restrict__ A,
                                                 const __bf16* __restrict__ BT,
                                                 const float* __restrict__ bias,
                                                 void* __restrict__ Cv,
                                                 int M, int ldc, int ncols) {
    constexpr int K = NK * 32;
    __shared__ __bf16 As[2][4096];
    __shared__ __bf16 Bs[2][4096];
    int t = threadIdx.x, w = t >> 6, lane = t & 63;
    int cb = lane & 15, rq = (lane >> 4) * 4;
    int n0 = blockIdx.x * 128, m0 = blockIdx.y * 128;

    int sr = lane & 15;
    int sk = (lane >> 4) * 8;
    int ar0 = m0 + (2 * w) * 16 + sr;     if (ar0 >= M) ar0 = M - 1;
    int ar1 = m0 + (2 * w + 1) * 16 + sr; if (ar1 >= M) ar1 = M - 1;
    const __bf16* ag0 = A + (size_t)ar0 * K + sk;
    const __bf16* ag1 = A + (size_t)ar1 * K + sk;
    const __bf16* bg0 = BT + (size_t)(n0 + (2 * w) * 16 + sr) * K + sk;
    const __bf16* bg1 = BT + (size_t)(n0 + (2 * w + 1) * 16 + sr) * K + sk;
    __bf16* la0[2] = { &As[0][(2 * w) * 512],     &As[1][(2 * w) * 512] };
    __bf16* la1[2] = { &As[0][(2 * w + 1) * 512], &As[1][(2 * w + 1) * 512] };
    __bf16* lb0[2] = { &Bs[0][(2 * w) * 512],     &Bs[1][(2 * w) * 512] };
    __bf16* lb1[2] = { &Bs[0][(2 * w + 1) * 512], &Bs[1][(2 * w + 1) * 512] };

    ld_lds16(ag0, la0[0]);
    ld_lds16(ag1, la1[0]);
    ld_lds16(bg0, lb0[0]);
    ld_lds16(bg1, lb1[0]);
    __syncthreads();

    int wm = w >> 1, wn = w & 1;
    f32x4 acc[4][4];
#pragma unroll
    for (int i = 0; i < 4; ++i)
#pragma unroll
        for (int j = 0; j < 4; ++j) acc[i][j] = (f32x4){0.f, 0.f, 0.f, 0.f};

#pragma unroll
    for (int ks = 0; ks < NK; ++ks) {
        int cur = ks & 1;
        if (ks + 1 < NK) {
            int nxt = cur ^ 1;
            ld_lds16(ag0 + (ks + 1) * 32, la0[nxt]);
            ld_lds16(ag1 + (ks + 1) * 32, la1[nxt]);
            ld_lds16(bg0 + (ks + 1) * 32, lb0[nxt]);
            ld_lds16(bg1 + (ks + 1) * 32, lb1[nxt]);
        }
        bf16x8 af[4], bfr[4];
#pragma unroll
        for (int i = 0; i < 4; ++i)
            af[i] = *(const bf16x8*)&As[cur][(wm * 4 + i) * 512 + lane * 8];
#pragma unroll
        for (int j = 0; j < 4; ++j)
            bfr[j] = *(const bf16x8*)&Bs[cur][(wn * 4 + j) * 512 + lane * 8];
#pragma unroll
        for (int j = 0; j < 4; ++j)
#pragma unroll
            for (int i = 0; i < 4; ++i)
                acc[i][j] = MFMA16(af[i], bfr[j], acc[i][j]);
        __syncthreads();
    }

#pragma unroll
    for (int j = 0; j < 4; ++j) {
        int col = n0 + (wn * 4 + j) * 16 + cb;
        float bb = 0.f;
        if (EPI >= 1 && col < ncols) bb = bias[col];
#pragma unroll
        for (int i = 0; i < 4; ++i) {
#pragma unroll
            for (int ii = 0; ii < 4; ++ii) {
                int row = m0 + (wm * 4 + i) * 16 + rq + ii;
                if (row >= M) continue;
                float v = acc[i][j][ii] + bb;
                if (EPI == 0) {
                    ((__bf16*)Cv)[(size_t)row * ldc + col] = (__bf16)v;
                } else if (EPI == 1) {
                    ((__bf16*)Cv)[(size_t)row * ldc + col] = (__bf16)fmaxf(v, 0.f);
                } else {
                    if (col < ncols)
                        ((float*)Cv)[(size_t)row * ldc + col] = v;
                }
            }
        }
    }
}

// ------------------------- MFMA GEMM + fused LayerNorm (1 wave / block) -----

template <int K, bool EMB>
__global__ __launch_bounds__(64) void gemm_ln(const void* __restrict__ Av,
                                              const __bf16* __restrict__ BT,
                                              const float* __restrict__ bias,
                                              const float* resid,
                                              const float* __restrict__ g,
                                              const float* __restrict__ beta,
                                              float* hout, __bf16* __restrict__ hbf,
                                              int M) {
    int wid = blockIdx.x;
    int lane = threadIdx.x;
    int m0 = wid * 16;
    if (m0 >= M) return;
    constexpr int KS = K / 32;
    int cb = lane & 15;
    int kc = (lane >> 4) * 8;
    int rq = (lane >> 4) * 4;
    int arow = m0 + cb;
    if (arow >= M) arow = M - 1;

    bf16x8 a[KS];
    if constexpr (EMB) {
        const float* A = (const float*)Av;
#pragma unroll
        for (int ks = 0; ks < KS; ++ks) {
            float4 u0 = *(const float4*)&A[(size_t)arow * K + ks * 32 + kc];
            float4 u1 = *(const float4*)&A[(size_t)arow * K + ks * 32 + kc + 4];
            bf16x8 av;
            av[0] = (__bf16)u0.x; av[1] = (__bf16)u0.y; av[2] = (__bf16)u0.z; av[3] = (__bf16)u0.w;
            av[4] = (__bf16)u1.x; av[5] = (__bf16)u1.y; av[6] = (__bf16)u1.z; av[7] = (__bf16)u1.w;
            a[ks] = av;
        }
    } else {
        const __bf16* A = (const __bf16*)Av;
#pragma unroll
        for (int ks = 0; ks < KS; ++ks)
            a[ks] = *(const bf16x8*)&A[(size_t)arow * K + ks * 32 + kc];
    }

    const __bf16* bbase = &BT[(size_t)cb * K + kc];
    bf16x8 bA[KS], bB[KS];
#pragma unroll
    for (int ks = 0; ks < KS; ++ks) bA[ks] = *(const bf16x8*)(bbase + ks * 32);

    f32x4 acc[8];
#pragma unroll
    for (int nt = 0; nt < 8; ++nt) acc[nt] = (f32x4){0.f, 0.f, 0.f, 0.f};

#pragma unroll
    for (int nt = 0; nt < 8; nt += 2) {
#pragma unroll
        for (int ks = 0; ks < KS; ++ks)
            bB[ks] = *(const bf16x8*)(bbase + (size_t)(nt + 1) * 16 * K + ks * 32);
#pragma unroll
        for (int ks = 0; ks < KS; ++ks)
            acc[nt] = MFMA16(a[ks], bA[ks], acc[nt]);
        if (nt + 2 < 8) {
#pragma unroll
            for (int ks = 0; ks < KS; ++ks)
                bA[ks] = *(const bf16x8*)(bbase + (size_t)(nt + 2) * 16 * K + ks * 32);
        }
#pragma unroll
        for (int ks = 0; ks < KS; ++ks)
            acc[nt + 1] = MFMA16(a[ks], bB[ks], acc[nt + 1]);
    }

#pragma unroll
    for (int nt = 0; nt < 8; ++nt) {
        int col = nt * 16 + cb;
        float bb = EMB ? bias[col] : 0.f;
#pragma unroll
        for (int i = 0; i < 4; ++i) {
            float v = acc[nt][i];
            if (EMB) {
                v = fmaxf(v + bb, 0.f);
            } else {
                int row = m0 + rq + i;
                if (row >= M) row = M - 1;
                v += resid[(size_t)row * 128 + col];
            }
            acc[nt][i] = v;
        }
    }

    float s[4] = {0.f, 0.f, 0.f, 0.f}, qs[4] = {0.f, 0.f, 0.f, 0.f};
#pragma unroll
    for (int nt = 0; nt < 8; ++nt)
#pragma unroll
        for (int i = 0; i < 4; ++i) {
            float v = acc[nt][i];
            s[i] += v;
            qs[i] += v * v;
        }
#pragma unroll
    for (int i = 0; i < 4; ++i)
#pragma unroll
        for (int o = 1; o < 16; o <<= 1) {
            s[i] += __shfl_xor(s[i], o);
            qs[i] += __shfl_xor(qs[i], o);
        }
    float mu[4], rstd[4];
#pragma unroll
    for (int i = 0; i < 4; ++i) {
        mu[i] = s[i] * (1.f / 128.f);
        float var = qs[i] * (1.f / 128.f) - mu[i] * mu[i];
        rstd[i] = rsqrtf(var + 1e-5f);
    }

#pragma unroll
    for (int nt = 0; nt < 8; ++nt) {
        int col = nt * 16 + cb;
        float gv = g[col], bv = beta[col];
#pragma unroll
        for (int i = 0; i < 4; ++i) {
            int row = m0 + rq + i;
            if (row >= M) continue;
            float y = (acc[nt][i] - mu[i]) * rstd[i] * gv + bv;
            size_t idx = (size_t)row * 128 + col;
            hout[idx] = y;
            hbf[idx] = (__bf16)y;
        }
    }
}

// ------------------------- attention (16 lanes x 4 edge slots) --------------

__global__ __launch_bounds__(256) void attn_gat(const __bf16* __restrict__ qkv,
                                                const int* __restrict__ row_ptr,
                                                const int* __restrict__ csr_src,
                                                __bf16* __restrict__ agg, int N) {
    int wave = threadIdx.x >> 6;
    int lane = threadIdx.x & 63;
    int n = blockIdx.x * 4 + wave;
    if (n >= N) return;
    int j = lane >> 4, q16 = lane & 15, c0 = q16 * 8;
    const float scale = 0.25f;  // 1/sqrt(16)

    bf16x8 qv = *(const bf16x8*)&qkv[(size_t)n * 384 + c0];
    float qf[8];
#pragma unroll
    for (int i = 0; i < 8; ++i) qf[i] = (float)qv[i];

    int e0 = row_ptr[n], e1 = row_ptr[n + 1];
    float m = -3e38f, s = 0.f;
    float acc[8] = {0.f, 0.f, 0.f, 0.f, 0.f, 0.f, 0.f, 0.f};

    for (int base = e0; base < e1; base += 4) {
        int e = base + j;
        bool valid = e < e1;
        int src = csr_src[valid ? e : e0];
        const __bf16* kp = &qkv[(size_t)src * 384 + 128 + c0];
        bf16x8 kv = *(const bf16x8*)kp;
        bf16x8 vv = *(const bf16x8*)(kp + 128);
        float d = 0.f;
#pragma unroll
        for (int i = 0; i < 8; ++i) d = fmaf(qf[i], (float)kv[i], d);
        d += __shfl_xor(d, 1);
        float sc = d * scale;
        if (valid) {
            float mn = fmaxf(m, sc);
            float f = __expf(m - mn), p = __expf(sc - mn);
            s = s * f + p;
#pragma unroll
            for (int i = 0; i < 8; ++i) acc[i] = acc[i] * f + p * (float)vv[i];
            m = mn;
        }
    }

#pragma unroll
    for (int off = 16; off <= 32; off <<= 1) {
        float mo_ = __shfl_xor(m, off);
        float so_ = __shfl_xor(s, off);
        float mn = fmaxf(m, mo_);
        float f = __expf(m - mn), fo = __expf(mo_ - mn);
        s = s * f + so_ * fo;
#pragma unroll
        for (int i = 0; i < 8; ++i)
            acc[i] = acc[i] * f + __shfl_xor(acc[i], off) * fo;
        m = mn;
    }

    if (j == 0) {
        float inv = (s > 0.f) ? 1.f / s : 0.f;
        bf16x8 o;
#pragma unroll
        for (int i = 0; i < 8; ++i) o[i] = (__bf16)(acc[i] * inv);
        *(bf16x8*)&agg[(size_t)n * 128 + c0] = o;
    }
}

// ------------------------- FFN head -----------------------------------------
// Block = 512 threads (8 waves), 64 rows. Wave w owns cols [w*64, w*64+64).
// Phase 2: A (h1) from swizzled LDS; B streamed DIRECT from L2 into registers
// with parity prefetch (no Bstage -> LDS 64KB -> 2 blocks/CU; per-step LDS
// traffic cut from 192B to 64B per thread).

__global__ __launch_bounds__(512) void ffn_mfma(const __bf16* __restrict__ hbf,
                                                const __bf16* __restrict__ f1T,
                                                const float* __restrict__ f1b,
                                                const __bf16* __restrict__ f2T,
                                                const float* __restrict__ f2b,
                                                const __bf16* __restrict__ f3T,
                                                const float* __restrict__ f3b,
                                                float* __restrict__ out, int M) {
    __shared__ __bf16 hbuf[64 * 512];  // 64 KB; byte = rl*1024+col*2 ^((rl&7)<<4)
    int w = threadIdx.x >> 6;
    int lane = threadIdx.x & 63;
    int r0 = blockIdx.x * 64;
    int cb = lane & 15;
    int kc = (lane >> 4) * 8;
    int rq = (lane >> 4) * 4;
    char* hb = (char*)hbuf;

    // ---- phase 1: h1 = relu(h @ f1w + b1); nt-outer, NT=4, MT=4, K=128
    {
        bf16x8 a1[4][4];
#pragma unroll
        for (int mt = 0; mt < 4; ++mt) {
            int row = r0 + mt * 16 + cb;
            if (row >= M) row = M - 1;
#pragma unroll
            for (int ks = 0; ks < 4; ++ks)
                a1[mt][ks] = *(const bf16x8*)&hbf[(size_t)row * 128 + ks * 32 + kc];
        }
        const __bf16* b1base = &f1T[(size_t)(w * 64 + cb) * 128 + kc];
        bf16x8 bA[4], bB[4];
#pragma unroll
        for (int ks = 0; ks < 4; ++ks) bA[ks] = *(const bf16x8*)(b1base + ks * 32);
#pragma unroll
        for (int nt = 0; nt < 4; nt += 2) {
#pragma unroll
            for (int ks = 0; ks < 4; ++ks)
                bB[ks] = *(const bf16x8*)(b1base + (size_t)(nt + 1) * 16 * 128 + ks * 32);
            {
                f32x4 acc[4];
#pragma unroll
                for (int mt = 0; mt < 4; ++mt) acc[mt] = (f32x4){0.f, 0.f, 0.f, 0.f};
#pragma unroll
                for (int ks = 0; ks < 4; ++ks)
#pragma unroll
                    for (int mt = 0; mt < 4; ++mt)
                        acc[mt] = MFMA16(a1[mt][ks], bA[ks], acc[mt]);
                int ncol = w * 64 + nt * 16;
                float bb = f1b[ncol + cb];
#pragma unroll
                for (int mt = 0; mt < 4; ++mt)
#pragma unroll
                    for (int i = 0; i < 4; ++i) {
                        int rl = mt * 16 + rq + i;
                        int byte = (rl * 1024 + (ncol + cb) * 2) ^ ((rl & 7) << 4);
                        *(__bf16*)(hb + byte) = (__bf16)fmaxf(acc[mt][i] + bb, 0.f);
                    }
            }
            if (nt + 2 < 4) {
#pragma unroll
                for (int ks = 0; ks < 4; ++ks)
                    bA[ks] = *(const bf16x8*)(b1base + (size_t)(nt + 2) * 16 * 128 + ks * 32);
            }
            {
                f32x4 acc[4];
#pragma unroll
                for (int mt = 0; mt < 4; ++mt) acc[mt] = (f32x4){0.f, 0.f, 0.f, 0.f};
#pragma unroll
                for (int ks = 0; ks < 4; ++ks)
#pragma unroll
                    for (int mt = 0; mt < 4; ++mt)
                        acc[mt] = MFMA16(a1[mt][ks], bB[ks], acc[mt]);
                int ncol = w * 64 + (nt + 1) * 16;
                float bb = f1b[ncol + cb];
#pragma unroll
                for (int mt = 0; mt < 4; ++mt)
#pragma unroll
                    for (int i = 0; i < 4; ++i) {
                        int rl = mt * 16 + rq + i;
                        int byte = (rl * 1024 + (ncol + cb) * 2) ^ ((rl & 7) << 4);
                        *(__bf16*)(hb + byte) = (__bf16)fmaxf(acc[mt][i] + bb, 0.f);
                    }
            }
        }
    }
    __syncthreads();

    // ---- phase 2: h2 = relu(h1 @ f2w + b2); K=512; A from LDS, B direct
    //      from L2 with parity prefetch. No barriers in the K-loop.
    {
        f32x4 acc2[4][4];
#pragma unroll
        for (int mt = 0; mt < 4; ++mt)
#pragma unroll
            for (int nt = 0; nt < 4; ++nt) acc2[mt][nt] = (f32x4){0.f, 0.f, 0.f, 0.f};

        const __bf16* bp[4];
#pragma unroll
        for (int nt = 0; nt < 4; ++nt)
            bp[nt] = &f2T[(size_t)(w * 64 + nt * 16 + cb) * 512 + kc];

        bf16x8 b0[4], b1[4];
#pragma unroll
        for (int nt = 0; nt < 4; ++nt) b0[nt] = *(const bf16x8*)bp[nt];

#pragma unroll
        for (int ks = 0; ks < 16; ks += 2) {
            // prefetch ks+1
#pragma unroll
            for (int nt = 0; nt < 4; ++nt)
                b1[nt] = *(const bf16x8*)(bp[nt] + (ks + 1) * 32);
            {
                bf16x8 a2[4];
#pragma unroll
                for (int mt = 0; mt < 4; ++mt) {
                    int rl = mt * 16 + cb;
                    int byte = (rl * 1024 + (ks * 32 + kc) * 2) ^ ((rl & 7) << 4);
                    a2[mt] = *(const bf16x8*)(hb + byte);
                }
#pragma unroll
                for (int nt = 0; nt < 4; ++nt)
#pragma unroll
                    for (int mt = 0; mt < 4; ++mt)
                        acc2[mt][nt] = MFMA16(a2[mt], b0[nt], acc2[mt][nt]);
            }
            // prefetch ks+2
            if (ks + 2 < 16) {
#pragma unroll
                for (int nt = 0; nt < 4; ++nt)
                    b0[nt] = *(const bf16x8*)(bp[nt] + (ks + 2) * 32);
            }
            {
                bf16x8 a2[4];
#pragma unroll
                for (int mt = 0; mt < 4; ++mt) {
                    int rl = mt * 16 + cb;
                    int byte = (rl * 1024 + ((ks + 1) * 32 + kc) * 2) ^ ((rl & 7) << 4);
                    a2[mt] = *(const bf16x8*)(hb + byte);
                }
#pragma unroll
                for (int nt = 0; nt < 4; ++nt)
#pragma unroll
                    for (int mt = 0; mt < 4; ++mt)
                        acc2[mt][nt] = MFMA16(a2[mt], b1[nt], acc2[mt][nt]);
            }
        }
        __syncthreads();  // all h1 reads done before overwrite

#pragma unroll
        for (int nt = 0; nt < 4; ++nt) {
            int ncol = w * 64 + nt * 16;
            float bb = f2b[ncol + cb];
#pragma unroll
            for (int mt = 0; mt < 4; ++mt)
#pragma unroll
                for (int i = 0; i < 4; ++i) {
                    int rl = mt * 16 + rq + i;
                    int byte = (rl * 1024 + (ncol + cb) * 2) ^ ((rl & 7) << 4);
                    *(__bf16*)(hb + byte) = (__bf16)fmaxf(acc2[mt][nt][i] + bb, 0.f);
                }
        }
    }
    __syncthreads();

    // ---- phase 3: out = h2 @ f3w + b3; waves 0..3 -> m-tile w, n-tiles 0..2
    if (w < 4) {
        f32x4 acc3[3];
#pragma unroll
        for (int nt = 0; nt < 3; ++nt) acc3[nt] = (f32x4){0.f, 0.f, 0.f, 0.f};
        const __bf16* b3base = &f3T[(size_t)cb * 512 + kc];
#pragma unroll
        for (int ks = 0; ks < 16; ++ks) {
            int rl = w * 16 + cb;
            int byte = (rl * 1024 + (ks * 32 + kc) * 2) ^ ((rl & 7) << 4);
            bf16x8 a3 = *(const bf16x8*)(hb + byte);
#pragma unroll
            for (int nt = 0; nt < 3; ++nt) {
                bf16x8 b = *(const bf16x8*)(b3base + (size_t)nt * 16 * 512 + ks * 32);
                acc3[nt] = MFMA16(a3, b, acc3[nt]);
            }
        }
#pragma unroll
        for (int nt = 0; nt < 3; ++nt) {
            int col = nt * 16 + cb;
            if (col < 47) {
                float bb = f3b[col];
                int r = r0 + w * 16 + rq;
#pragma unroll
                for (int i = 0; i < 4; ++i)
                    if (r + i < M) out[(size_t)(r + i) * 47 + col] = acc3[nt][i] + bb;
            }
        }
    }
}

// ------------------------- launch -------------------------------------------

extern "C" void kernel_launch(void* const* d_in, const int* in_sizes, int n_in,
                              void* d_out, int out_size, void* d_ws, size_t ws_size,
                              hipStream_t stream) {
    const float* X        = (const float*)d_in[0];
    const int*   ei       = (const int*)d_in[1];
    const float* emb_w    = (const float*)d_in[2];
    const float* emb_b    = (const float*)d_in[3];
    const float* emb_ln_g = (const float*)d_in[4];
    const float* emb_ln_b = (const float*)d_in[5];
    const float* Wq       = (const float*)d_in[6];
    const float* Wk       = (const float*)d_in[7];
    const float* Wv       = (const float*)d_in[8];
    const float* Wo       = (const float*)d_in[9];
    const float* ln_g     = (const float*)d_in[10];
    const float* ln_b     = (const float*)d_in[11];
    const float* f1w      = (const float*)d_in[12];
    const float* f1b      = (const float*)d_in[13];
    const float* f2w      = (const float*)d_in[14];
    const float* f2b      = (const float*)d_in[15];
    const float* f3w      = (const float*)d_in[16];
    const float* f3b      = (const float*)d_in[17];

    const int N = in_sizes[0] / 256;  // 50000
    const int E = in_sizes[1] / 2;    // 640000
    const int NB = (N + 1023) / 1024;

    // ---- workspace layout
    char* p = (char*)d_ws;
    float* h = (float*)p;            p += (size_t)N * 128 * 4;
    __bf16* hbf = (__bf16*)p;        p += (size_t)N * 128 * 2;
    __bf16* qkv = (__bf16*)p;        p += (size_t)N * 384 * 2;
    __bf16* aggb = (__bf16*)p;       p += (size_t)N * 128 * 2;
    __bf16* embT = (__bf16*)p;       p += 128 * 256 * 2;
    __bf16* qkvT = (__bf16*)p;       p += 3 * 384 * 128 * 2;
    __bf16* woT = (__bf16*)p;        p += 3 * 128 * 128 * 2;
    __bf16* f1T = (__bf16*)p;        p += 512 * 128 * 2;
    __bf16* f2T = (__bf16*)p;        p += 512 * 512 * 2;
    __bf16* f3T = (__bf16*)p;        p += 48 * 512 * 2;
    int* deg = (int*)p;              p += (size_t)N * 4;
    int* cursor = (int*)p;           p += (size_t)N * 4;
    int* row_ptr = (int*)p;          p += (size_t)(N + 1) * 4;
    int* csr_src = (int*)p;          p += (size_t)E * 4;
    int* partials = (int*)p;

    // ---- CSR build
    zero_ints<<<(2 * N + 255) / 256, 256, 0, stream>>>(deg, 2 * N);
    count_deg<<<(E + 255) / 256, 256, 0, stream>>>(ei, deg, E);
    scan_part<<<NB, 256, 0, stream>>>(deg, partials, N);
    scan_mid<<<1, 64, 0, stream>>>(partials, row_ptr, NB, N);
    scan_final<<<NB, 256, 0, stream>>>(deg, partials, row_ptr, N);
    scatter_edges<<<(E + 255) / 256, 256, 0, stream>>>(ei, row_ptr, cursor, csr_src, E);

    transpose_all<<<576, 256, 0, stream>>>(emb_w, f1w, f2w, f3w, Wq, Wk, Wv, Wo,
                                           embT, f1T, f2T, f3T, qkvT, woT);

    int gwave = (N + 15) / 16;    // 3125 one-wave blocks for gemm_ln
    int gm128 = (N + 127) / 128;  // 391 row panels for gemm_tile

    // ---- embedding: LN(relu(X @ emb_w + emb_b)) -> h (fp32) + hbf
    gemm_ln<256, true><<<gwave, 64, 0, stream>>>(X, embT, emb_b, nullptr,
                                                 emb_ln_g, emb_ln_b, h, hbf, N);

    // ---- layers
    for (int l = 0; l < 3; ++l) {
        gemm_tile<4, 0><<<dim3(3, gm128), 256, 0, stream>>>(
            hbf, qkvT + (size_t)l * 49152, nullptr, qkv, N, 384, 384);
        attn_gat<<<(N + 3) / 4, 256, 0, stream>>>(qkv, row_ptr, csr_src, aggb, N);
        gemm_ln<128, false><<<gwave, 64, 0, stream>>>(aggb, woT + (size_t)l * 16384,
                                                      nullptr, h,
                                                      ln_g + (size_t)l * 128,
                                                      ln_b + (size_t)l * 128, h, hbf, N);
    }

    // ---- FFN head
    ffn_mfma<<<(N + 63) / 64, 512, 0, stream>>>(hbf, f1T, f1b, f2T, f2b, f3T, f3b,
                                                (float*)d_out, N);
}

// Round 13
// 492.577 us; speedup vs baseline: 1.1054x; 1.1054x over previous
//
#include <hip/hip_runtime.h>
#include <hip/hip_bf16.h>
#include <math.h>

// ---------------------------------------------------------------------------
// GraphMemoryNetwork — Round 13: fragment-packed FFN weights (coalesced B,
// no over-fetch) + software-pipelined attention gathers.
// N=50000, E=640000, D_IN=256, D=128, H=8, DH=16, NC=47, L=3
// ---------------------------------------------------------------------------

typedef __bf16 bf16x8 __attribute__((ext_vector_type(8)));
typedef float  f32x4  __attribute__((ext_vector_type(4)));

#define MFMA16(a, b, c) __builtin_amdgcn_mfma_f32_16x16x32_bf16((a), (b), (c), 0, 0, 0)

// async 16B/lane global -> LDS (wave-uniform LDS base + lane*16)
__device__ __forceinline__ void ld_lds16(const __bf16* g, __bf16* l) {
    __builtin_amdgcn_global_load_lds(
        (__attribute__((address_space(1))) void*)g,
        (__attribute__((address_space(3))) void*)l, 16, 0, 0);
}

// ------------------------- CSR build ---------------------------------------

__global__ __launch_bounds__(256) void count_deg(const int* __restrict__ ei,
                                                 int* __restrict__ deg, int E) {
    int e = blockIdx.x * 256 + threadIdx.x;
    if (e < E) atomicAdd(&deg[ei[(size_t)E + e]], 1);   // dst = ei[1][e]
}

__global__ __launch_bounds__(256) void scan_part(const int* __restrict__ deg,
                                                 int* __restrict__ partials, int N) {
    int b = blockIdx.x, t = threadIdx.x, lane = t & 63, w = t >> 6;
    int base = b * 1024 + t * 4;
    int4 v = make_int4(0, 0, 0, 0);
    if (base + 3 < N) v = *(const int4*)&deg[base];
    else {
        if (base < N)     v.x = deg[base];
        if (base + 1 < N) v.y = deg[base + 1];
        if (base + 2 < N) v.z = deg[base + 2];
    }
    int s = v.x + v.y + v.z + v.w;
#pragma unroll
    for (int o = 1; o < 64; o <<= 1) s += __shfl_xor(s, o);
    __shared__ int ws[4];
    if (lane == 0) ws[w] = s;
    __syncthreads();
    if (t == 0) partials[b] = ws[0] + ws[1] + ws[2] + ws[3];
}

__global__ __launch_bounds__(64) void scan_mid(int* __restrict__ partials,
                                               int* __restrict__ row_ptr,
                                               int nb, int N) {
    int t = threadIdx.x;
    int v = (t < nb) ? partials[t] : 0;
    int incl = v;
#pragma unroll
    for (int o = 1; o < 64; o <<= 1) {
        int u = __shfl_up(incl, o);
        if (t >= o) incl += u;
    }
    if (t < nb) partials[t] = incl - v;
    if (t == nb - 1) row_ptr[N] = incl;
}

__global__ __launch_bounds__(256) void scan_final(const int* __restrict__ deg,
                                                  const int* __restrict__ partials,
                                                  int* __restrict__ row_ptr, int N) {
    int b = blockIdx.x, t = threadIdx.x, lane = t & 63, w = t >> 6;
    int base = b * 1024 + t * 4;
    int4 v = make_int4(0, 0, 0, 0);
    if (base + 3 < N) v = *(const int4*)&deg[base];
    else {
        if (base < N)     v.x = deg[base];
        if (base + 1 < N) v.y = deg[base + 1];
        if (base + 2 < N) v.z = deg[base + 2];
    }
    int c1 = v.x, c2 = c1 + v.y, c3 = c2 + v.z, c4 = c3 + v.w;
    int s = c4, incl = s;
#pragma unroll
    for (int o = 1; o < 64; o <<= 1) {
        int u = __shfl_up(incl, o);
        if (lane >= o) incl += u;
    }
    int texcl = incl - s;
    __shared__ int ws[4];
    if (lane == 63) ws[w] = incl;
    __syncthreads();
    int woff = 0;
    for (int i = 0; i < w; ++i) woff += ws[i];
    int off = partials[b] + woff + texcl;
    if (base < N)     row_ptr[base]     = off;
    if (base + 1 < N) row_ptr[base + 1] = off + c1;
    if (base + 2 < N) row_ptr[base + 2] = off + c2;
    if (base + 3 < N) row_ptr[base + 3] = off + c3;
}

__global__ __launch_bounds__(256) void scatter_edges(const int* __restrict__ ei,
                                                     const int* __restrict__ row_ptr,
                                                     int* __restrict__ cursor,
                                                     int* __restrict__ csr_src, int E) {
    int e = blockIdx.x * 256 + threadIdx.x;
    if (e < E) {
        int d = ei[(size_t)E + e];
        int pos = row_ptr[d] + atomicAdd(&cursor[d], 1);
        csr_src[pos] = ei[e];
    }
}

// ------------------------- batched weight transpose -------------------------

__global__ __launch_bounds__(256) void transpose_all(
    const float* __restrict__ emb_w, const float* __restrict__ f1w,
    const float* __restrict__ f2w, const float* __restrict__ f3w,
    const float* __restrict__ Wq, const float* __restrict__ Wk,
    const float* __restrict__ Wv, const float* __restrict__ Wo,
    __bf16* __restrict__ embT, __bf16* __restrict__ f1T,
    __bf16* __restrict__ f2T, __bf16* __restrict__ f3T,
    __bf16* __restrict__ qkvT, __bf16* __restrict__ woT) {
    __shared__ float tile[32][33];
    int t = blockIdx.x;
    const float* src; __bf16* dst; int K, Nin, Npad, nxt;
    if (t < 32)       { src = emb_w; dst = embT; K = 256; Nin = 128; Npad = 128; nxt = 4; }
    else if (t < 96)  { t -= 32;  src = f1w; dst = f1T; K = 128; Nin = 512; Npad = 512; nxt = 16; }
    else if (t < 352) { t -= 96;  src = f2w; dst = f2T; K = 512; Nin = 512; Npad = 512; nxt = 16; }
    else if (t < 384) { t -= 352; src = f3w; dst = f3T; K = 512; Nin = 47;  Npad = 48;  nxt = 2; }
    else {
        t -= 384;
        int mat = t >> 4; t &= 15;
        int l = mat >> 2, m = mat & 3;
        src = (m == 0 ? Wq : m == 1 ? Wk : m == 2 ? Wv : Wo) + (size_t)l * 16384;
        dst = (m < 3) ? qkvT + (size_t)l * 49152 + (size_t)m * 16384
                      : woT + (size_t)l * 16384;
        K = 128; Nin = 128; Npad = 128; nxt = 4;
    }
    int n0 = (t % nxt) * 32, k0 = (t / nxt) * 32;
    int tx = threadIdx.x & 31, ty = threadIdx.x >> 5;
#pragma unroll
    for (int i = 0; i < 32; i += 8) {
        int k = k0 + ty + i, n = n0 + tx;
        tile[ty + i][tx] = (k < K && n < Nin) ? src[(size_t)k * Nin + n] : 0.f;
    }
    __syncthreads();
#pragma unroll
    for (int i = 0; i < 32; i += 8) {
        int n = n0 + ty + i, k = k0 + tx;
        if (n < Npad && k < K) dst[(size_t)n * K + k] = (__bf16)tile[tx][ty + i];
    }
}

// ------------------------- fragment packer ----------------------------------
// P[(tile*NKS + ks)*64 + lane] (16B each) = BT[(tile*16 + (lane&15)) * K
//   + ks*32 + (lane>>4)*8 .. +8].  Wave load for fragment (tile,ks) is a
//   contiguous 1KB block -> perfectly coalesced MFMA B operands.
// f1: 32 tiles, NKS=4 (8192 frags) | f2: 32 tiles, NKS=16 (32768) |
// f3: 3 tiles, NKS=16 (3072). Total 44032 fragments.

__global__ __launch_bounds__(256) void pack_frag(const __bf16* __restrict__ f1T,
                                                 const __bf16* __restrict__ f2T,
                                                 const __bf16* __restrict__ f3T,
                                                 __bf16* __restrict__ f1P,
                                                 __bf16* __restrict__ f2P,
                                                 __bf16* __restrict__ f3P) {
    int idx = blockIdx.x * 256 + threadIdx.x;
    const __bf16* src; __bf16* dst; int K, base;
    if (idx < 8192)        { src = f1T; dst = f1P; K = 128; base = idx; }
    else if (idx < 40960)  { src = f2T; dst = f2P; K = 512; base = idx - 8192; }
    else if (idx < 44032)  { src = f3T; dst = f3P; K = 512; base = idx - 40960; }
    else return;
    int lane = base & 63;
    int nks = K / 32;
    int ks = (base >> 6) % nks;
    int tile = base / (64 * nks);
    int cb = lane & 15, kcg = lane >> 4;
    bf16x8 v = *(const bf16x8*)&src[(size_t)(tile * 16 + cb) * K + ks * 32 + kcg * 8];
    *(bf16x8*)&dst[(size_t)base * 8] = v;
}

// ------------------------- block-tiled MFMA GEMM (async LDS staging) --------

template <int NK, int EPI>
__global__ __launch_bounds__(256) void gemm_tile(const __bf16* __restrict__ A,
                                                 const __bf16* __restrict__ BT,
                                                 const float* __restrict__ bias,
                                                 void* __restrict__ Cv,
                                                 int M, int ldc, int ncols) {
    constexpr int K = NK * 32;
    __shared__ __bf16 As[2][4096];
    __shared__ __bf16 Bs[2][4096];
    int t = threadIdx.x, w = t >> 6, lane = t & 63;
    int cb = lane & 15, rq = (lane >> 4) * 4;
    int n0 = blockIdx.x * 128, m0 = blockIdx.y * 128;

    int sr = lane & 15;
    int sk = (lane >> 4) * 8;
    int ar0 = m0 + (2 * w) * 16 + sr;     if (ar0 >= M) ar0 = M - 1;
    int ar1 = m0 + (2 * w + 1) * 16 + sr; if (ar1 >= M) ar1 = M - 1;
    const __bf16* ag0 = A + (size_t)ar0 * K + sk;
    const __bf16* ag1 = A + (size_t)ar1 * K + sk;
    const __bf16* bg0 = BT + (size_t)(n0 + (2 * w) * 16 + sr) * K + sk;
    const __bf16* bg1 = BT + (size_t)(n0 + (2 * w + 1) * 16 + sr) * K + sk;
    __bf16* la0[2] = { &As[0][(2 * w) * 512],     &As[1][(2 * w) * 512] };
    __bf16* la1[2] = { &As[0][(2 * w + 1) * 512], &As[1][(2 * w + 1) * 512] };
    __bf16* lb0[2] = { &Bs[0][(2 * w) * 512],     &Bs[1][(2 * w) * 512] };
    __bf16* lb1[2] = { &Bs[0][(2 * w + 1) * 512], &Bs[1][(2 * w + 1) * 512] };

    ld_lds16(ag0, la0[0]);
    ld_lds16(ag1, la1[0]);
    ld_lds16(bg0, lb0[0]);
    ld_lds16(bg1, lb1[0]);
    __syncthreads();

    int wm = w >> 1, wn = w & 1;
    f32x4 acc[4][4];
#pragma unroll
    for (int i = 0; i < 4; ++i)
#pragma unroll
        for (int j = 0; j < 4; ++j) acc[i][j] = (f32x4){0.f, 0.f, 0.f, 0.f};

#pragma unroll
    for (int ks = 0; ks < NK; ++ks) {
        int cur = ks & 1;
        if (ks + 1 < NK) {
            int nxt = cur ^ 1;
            ld_lds16(ag0 + (ks + 1) * 32, la0[nxt]);
            ld_lds16(ag1 + (ks + 1) * 32, la1[nxt]);
            ld_lds16(bg0 + (ks + 1) * 32, lb0[nxt]);
            ld_lds16(bg1 + (ks + 1) * 32, lb1[nxt]);
        }
        bf16x8 af[4], bfr[4];
#pragma unroll
        for (int i = 0; i < 4; ++i)
            af[i] = *(const bf16x8*)&As[cur][(wm * 4 + i) * 512 + lane * 8];
#pragma unroll
        for (int j = 0; j < 4; ++j)
            bfr[j] = *(const bf16x8*)&Bs[cur][(wn * 4 + j) * 512 + lane * 8];
#pragma unroll
        for (int j = 0; j < 4; ++j)
#pragma unroll
            for (int i = 0; i < 4; ++i)
                acc[i][j] = MFMA16(af[i], bfr[j], acc[i][j]);
        __syncthreads();
    }

#pragma unroll
    for (int j = 0; j < 4; ++j) {
        int col = n0 + (wn * 4 + j) * 16 + cb;
        float bb = 0.f;
        if (EPI >= 1 && col < ncols) bb = bias[col];
#pragma unroll
        for (int i = 0; i < 4; ++i) {
#pragma unroll
            for (int ii = 0; ii < 4; ++ii) {
                int row = m0 + (wm * 4 + i) * 16 + rq + ii;
                if (row >= M) continue;
                float v = acc[i][j][ii] + bb;
                if (EPI == 0) {
                    ((__bf16*)Cv)[(size_t)row * ldc + col] = (__bf16)v;
                } else if (EPI == 1) {
                    ((__bf16*)Cv)[(size_t)row * ldc + col] = (__bf16)fmaxf(v, 0.f);
                } else {
                    if (col < ncols)
                        ((float*)Cv)[(size_t)row * ldc + col] = v;
                }
            }
        }
    }
}

// ------------------------- MFMA GEMM + fused LayerNorm (1 wave / block) -----

template <int K, bool EMB>
__global__ __launch_bounds__(64) void gemm_ln(const void* __restrict__ Av,
                                              const __bf16* __restrict__ BT,
                                              const float* __restrict__ bias,
                                              const float* resid,
                                              const float* __restrict__ g,
                                              const float* __restrict__ beta,
                                              float* hout, __bf16* __restrict__ hbf,
                                              int M) {
    int wid = blockIdx.x;
    int lane = threadIdx.x;
    int m0 = wid * 16;
    if (m0 >= M) return;
    constexpr int KS = K / 32;
    int cb = lane & 15;
    int kc = (lane >> 4) * 8;
    int rq = (lane >> 4) * 4;
    int arow = m0 + cb;
    if (arow >= M) arow = M - 1;

    bf16x8 a[KS];
    if constexpr (EMB) {
        const float* A = (const float*)Av;
#pragma unroll
        for (int ks = 0; ks < KS; ++ks) {
            float4 u0 = *(const float4*)&A[(size_t)arow * K + ks * 32 + kc];
            float4 u1 = *(const float4*)&A[(size_t)arow * K + ks * 32 + kc + 4];
            bf16x8 av;
            av[0] = (__bf16)u0.x; av[1] = (__bf16)u0.y; av[2] = (__bf16)u0.z; av[3] = (__bf16)u0.w;
            av[4] = (__bf16)u1.x; av[5] = (__bf16)u1.y; av[6] = (__bf16)u1.z; av[7] = (__bf16)u1.w;
            a[ks] = av;
        }
    } else {
        const __bf16* A = (const __bf16*)Av;
#pragma unroll
        for (int ks = 0; ks < KS; ++ks)
            a[ks] = *(const bf16x8*)&A[(size_t)arow * K + ks * 32 + kc];
    }

    const __bf16* bbase = &BT[(size_t)cb * K + kc];
    bf16x8 bA[KS], bB[KS];
#pragma unroll
    for (int ks = 0; ks < KS; ++ks) bA[ks] = *(const bf16x8*)(bbase + ks * 32);

    f32x4 acc[8];
#pragma unroll
    for (int nt = 0; nt < 8; ++nt) acc[nt] = (f32x4){0.f, 0.f, 0.f, 0.f};

#pragma unroll
    for (int nt = 0; nt < 8; nt += 2) {
#pragma unroll
        for (int ks = 0; ks < KS; ++ks)
            bB[ks] = *(const bf16x8*)(bbase + (size_t)(nt + 1) * 16 * K + ks * 32);
#pragma unroll
        for (int ks = 0; ks < KS; ++ks)
            acc[nt] = MFMA16(a[ks], bA[ks], acc[nt]);
        if (nt + 2 < 8) {
#pragma unroll
            for (int ks = 0; ks < KS; ++ks)
                bA[ks] = *(const bf16x8*)(bbase + (size_t)(nt + 2) * 16 * K + ks * 32);
        }
#pragma unroll
        for (int ks = 0; ks < KS; ++ks)
            acc[nt + 1] = MFMA16(a[ks], bB[ks], acc[nt + 1]);
    }

#pragma unroll
    for (int nt = 0; nt < 8; ++nt) {
        int col = nt * 16 + cb;
        float bb = EMB ? bias[col] : 0.f;
#pragma unroll
        for (int i = 0; i < 4; ++i) {
            float v = acc[nt][i];
            if (EMB) {
                v = fmaxf(v + bb, 0.f);
            } else {
                int row = m0 + rq + i;
                if (row >= M) row = M - 1;
                v += resid[(size_t)row * 128 + col];
            }
            acc[nt][i] = v;
        }
    }

    float s[4] = {0.f, 0.f, 0.f, 0.f}, qs[4] = {0.f, 0.f, 0.f, 0.f};
#pragma unroll
    for (int nt = 0; nt < 8; ++nt)
#pragma unroll
        for (int i = 0; i < 4; ++i) {
            float v = acc[nt][i];
            s[i] += v;
            qs[i] += v * v;
        }
#pragma unroll
    for (int i = 0; i < 4; ++i)
#pragma unroll
        for (int o = 1; o < 16; o <<= 1) {
            s[i] += __shfl_xor(s[i], o);
            qs[i] += __shfl_xor(qs[i], o);
        }
    float mu[4], rstd[4];
#pragma unroll
    for (int i = 0; i < 4; ++i) {
        mu[i] = s[i] * (1.f / 128.f);
        float var = qs[i] * (1.f / 128.f) - mu[i] * mu[i];
        rstd[i] = rsqrtf(var + 1e-5f);
    }

#pragma unroll
    for (int nt = 0; nt < 8; ++nt) {
        int col = nt * 16 + cb;
        float gv = g[col], bv = beta[col];
#pragma unroll
        for (int i = 0; i < 4; ++i) {
            int row = m0 + rq + i;
            if (row >= M) continue;
            float y = (acc[nt][i] - mu[i]) * rstd[i] * gv + bv;
            size_t idx = (size_t)row * 128 + col;
            hout[idx] = y;
            hbf[idx] = (__bf16)y;
        }
    }
}

// ------------------------- attention (pipelined gathers) --------------------
// One wave per dst node; 4 edge slots x 16 lanes (8 ch each). Gathers for
// iteration i+1 issued during iteration i; edge indices prefetched 2 deep.

__global__ __launch_bounds__(256) void attn_gat(const __bf16* __restrict__ qkv,
                                                const int* __restrict__ row_ptr,
                                                const int* __restrict__ csr_src,
                                                __bf16* __restrict__ agg, int N) {
    int wave = threadIdx.x >> 6;
    int lane = threadIdx.x & 63;
    int n = blockIdx.x * 4 + wave;
    if (n >= N) return;
    int j = lane >> 4, q16 = lane & 15, c0 = q16 * 8;
    const float scale = 0.25f;  // 1/sqrt(16)

    int e0 = row_ptr[n], e1 = row_ptr[n + 1];

    bf16x8 qv = *(const bf16x8*)&qkv[(size_t)n * 384 + c0];
    float qf[8];
#pragma unroll
    for (int i = 0; i < 8; ++i) qf[i] = (float)qv[i];

    float m = -3e38f, s = 0.f;
    float acc[8] = {0.f, 0.f, 0.f, 0.f, 0.f, 0.f, 0.f, 0.f};

    if (e0 < e1) {
        // prologue: idx + gather for iter 0, idx for iter 1
        int e = e0 + j;
        bool v0 = e < e1;
        int i0 = csr_src[v0 ? e : e0];
        const __bf16* kp0 = &qkv[(size_t)i0 * 384 + 128 + c0];
        bf16x8 k0 = *(const bf16x8*)kp0;
        bf16x8 vv0 = *(const bf16x8*)(kp0 + 128);
        int en = e0 + 4 + j;
        bool v1 = en < e1;
        int i1 = csr_src[v1 ? en : e0];

        for (int base = e0; base < e1; base += 4) {
            // issue gathers for iter+1
            bf16x8 k1, vv1;
            if (base + 4 < e1) {
                const __bf16* kp1 = &qkv[(size_t)i1 * 384 + 128 + c0];
                k1 = *(const bf16x8*)kp1;
                vv1 = *(const bf16x8*)(kp1 + 128);
            }
            // prefetch idx for iter+2
            int e2 = base + 8 + j;
            bool v2 = e2 < e1;
            int i2 = csr_src[v2 ? e2 : e0];

            // compute with iter-i data (waits land here)
            float d = 0.f;
#pragma unroll
            for (int i = 0; i < 8; ++i) d = fmaf(qf[i], (float)k0[i], d);
            d += __shfl_xor(d, 1);
            float sc = d * scale;
            if (v0) {
                float mn = fmaxf(m, sc);
                float f = __expf(m - mn), p = __expf(sc - mn);
                s = s * f + p;
#pragma unroll
                for (int i = 0; i < 8; ++i) acc[i] = acc[i] * f + p * (float)vv0[i];
                m = mn;
            }
            // rotate
            k0 = k1; vv0 = vv1; v0 = v1;
            i1 = i2; v1 = v2;
        }
    }

    // merge 4 slots (lane bits 4 and 5)
#pragma unroll
    for (int off = 16; off <= 32; off <<= 1) {
        float mo_ = __shfl_xor(m, off);
        float so_ = __shfl_xor(s, off);
        float mn = fmaxf(m, mo_);
        float f = __expf(m - mn), fo = __expf(mo_ - mn);
        s = s * f + so_ * fo;
#pragma unroll
        for (int i = 0; i < 8; ++i)
            acc[i] = acc[i] * f + __shfl_xor(acc[i], off) * fo;
        m = mn;
    }

    if (j == 0) {
        float inv = (s > 0.f) ? 1.f / s : 0.f;
        bf16x8 o;
#pragma unroll
        for (int i = 0; i < 8; ++i) o[i] = (__bf16)(acc[i] * inv);
        *(bf16x8*)&agg[(size_t)n * 128 + c0] = o;
    }
}

// ------------------------- FFN head -----------------------------------------
// Block = 512 threads (8 waves), 64 rows. Wave w owns cols [w*64, w*64+64).
// All B operands from fragment-packed weights (contiguous 1KB per fragment).
// Phase 2: A (h1) from swizzled LDS; B direct with parity prefetch.

__global__ __launch_bounds__(512) void ffn_mfma(const __bf16* __restrict__ hbf,
                                                const __bf16* __restrict__ f1P,
                                                const float* __restrict__ f1b,
                                                const __bf16* __restrict__ f2P,
                                                const float* __restrict__ f2b,
                                                const __bf16* __restrict__ f3P,
                                                const float* __restrict__ f3b,
                                                float* __restrict__ out, int M) {
    __shared__ __bf16 hbuf[64 * 512];  // 64 KB; byte = rl*1024+col*2 ^((rl&7)<<4)
    int w = threadIdx.x >> 6;
    int lane = threadIdx.x & 63;
    int r0 = blockIdx.x * 64;
    int cb = lane & 15;
    int kc = (lane >> 4) * 8;
    int rq = (lane >> 4) * 4;
    char* hb = (char*)hbuf;

    // ---- phase 1: h1 = relu(h @ f1w + b1); NT=4, MT=4, K=128 (NKS=4)
    {
        bf16x8 a1[4][4];
#pragma unroll
        for (int mt = 0; mt < 4; ++mt) {
            int row = r0 + mt * 16 + cb;
            if (row >= M) row = M - 1;
#pragma unroll
            for (int ks = 0; ks < 4; ++ks)
                a1[mt][ks] = *(const bf16x8*)&hbf[(size_t)row * 128 + ks * 32 + kc];
        }
        // fragment (nt, ks) for this wave: f1P + ((w*4+nt)*4 + ks)*512 + lane*8
        const __bf16* b1p = f1P + (size_t)(w * 4) * 4 * 512 + lane * 8;
        bf16x8 bA[4], bB[4];
#pragma unroll
        for (int ks = 0; ks < 4; ++ks) bA[ks] = *(const bf16x8*)(b1p + ks * 512);
#pragma unroll
        for (int nt = 0; nt < 4; nt += 2) {
#pragma unroll
            for (int ks = 0; ks < 4; ++ks)
                bB[ks] = *(const bf16x8*)(b1p + ((nt + 1) * 4 + ks) * 512);
            {
                f32x4 acc[4];
#pragma unroll
                for (int mt = 0; mt < 4; ++mt) acc[mt] = (f32x4){0.f, 0.f, 0.f, 0.f};
#pragma unroll
                for (int ks = 0; ks < 4; ++ks)
#pragma unroll
                    for (int mt = 0; mt < 4; ++mt)
                        acc[mt] = MFMA16(a1[mt][ks], bA[ks], acc[mt]);
                int ncol = w * 64 + nt * 16;
                float bb = f1b[ncol + cb];
#pragma unroll
                for (int mt = 0; mt < 4; ++mt)
#pragma unroll
                    for (int i = 0; i < 4; ++i) {
                        int rl = mt * 16 + rq + i;
                        int byte = (rl * 1024 + (ncol + cb) * 2) ^ ((rl & 7) << 4);
                        *(__bf16*)(hb + byte) = (__bf16)fmaxf(acc[mt][i] + bb, 0.f);
                    }
            }
            if (nt + 2 < 4) {
#pragma unroll
                for (int ks = 0; ks < 4; ++ks)
                    bA[ks] = *(const bf16x8*)(b1p + ((nt + 2) * 4 + ks) * 512);
            }
            {
                f32x4 acc[4];
#pragma unroll
                for (int mt = 0; mt < 4; ++mt) acc[mt] = (f32x4){0.f, 0.f, 0.f, 0.f};
#pragma unroll
                for (int ks = 0; ks < 4; ++ks)
#pragma unroll
                    for (int mt = 0; mt < 4; ++mt)
                        acc[mt] = MFMA16(a1[mt][ks], bB[ks], acc[mt]);
                int ncol = w * 64 + (nt + 1) * 16;
                float bb = f1b[ncol + cb];
#pragma unroll
                for (int mt = 0; mt < 4; ++mt)
#pragma unroll
                    for (int i = 0; i < 4; ++i) {
                        int rl = mt * 16 + rq + i;
                        int byte = (rl * 1024 + (ncol + cb) * 2) ^ ((rl & 7) << 4);
                        *(__bf16*)(hb + byte) = (__bf16)fmaxf(acc[mt][i] + bb, 0.f);
                    }
            }
        }
    }
    __syncthreads();

    // ---- phase 2: h2 = relu(h1 @ f2w + b2); K=512 (NKS=16); A from LDS,
    //      B from packed fragments with parity prefetch. No K-loop barriers.
    {
        f32x4 acc2[4][4];
#pragma unroll
        for (int mt = 0; mt < 4; ++mt)
#pragma unroll
            for (int nt = 0; nt < 4; ++nt) acc2[mt][nt] = (f32x4){0.f, 0.f, 0.f, 0.f};

        // fragment (nt, ks): f2P + ((w*4+nt)*16 + ks)*512 + lane*8
        const __bf16* b2p = f2P + (size_t)(w * 4) * 16 * 512 + lane * 8;

        bf16x8 b0[4], b1[4];
#pragma unroll
        for (int nt = 0; nt < 4; ++nt) b0[nt] = *(const bf16x8*)(b2p + nt * 16 * 512);

#pragma unroll
        for (int ks = 0; ks < 16; ks += 2) {
#pragma unroll
            for (int nt = 0; nt < 4; ++nt)
                b1[nt] = *(const bf16x8*)(b2p + (nt * 16 + ks + 1) * 512);
            {
                bf16x8 a2[4];
#pragma unroll
                for (int mt = 0; mt < 4; ++mt) {
                    int rl = mt * 16 + cb;
                    int byte = (rl * 1024 + (ks * 32 + kc) * 2) ^ ((rl & 7) << 4);
                    a2[mt] = *(const bf16x8*)(hb + byte);
                }
#pragma unroll
                for (int nt = 0; nt < 4; ++nt)
#pragma unroll
                    for (int mt = 0; mt < 4; ++mt)
                        acc2[mt][nt] = MFMA16(a2[mt], b0[nt], acc2[mt][nt]);
            }
            if (ks + 2 < 16) {
#pragma unroll
                for (int nt = 0; nt < 4; ++nt)
                    b0[nt] = *(const bf16x8*)(b2p + (nt * 16 + ks + 2) * 512);
            }
            {
                bf16x8 a2[4];
#pragma unroll
                for (int mt = 0; mt < 4; ++mt) {
                    int rl = mt * 16 + cb;
                    int byte = (rl * 1024 + ((ks + 1) * 32 + kc) * 2) ^ ((rl & 7) << 4);
                    a2[mt] = *(const bf16x8*)(hb + byte);
                }
#pragma unroll
                for (int nt = 0; nt < 4; ++nt)
#pragma unroll
                    for (int mt = 0; mt < 4; ++mt)
                        acc2[mt][nt] = MFMA16(a2[mt], b1[nt], acc2[mt][nt]);
            }
        }
        __syncthreads();  // all h1 reads done before overwrite

#pragma unroll
        for (int nt = 0; nt < 4; ++nt) {
            int ncol = w * 64 + nt * 16;
            float bb = f2b[ncol + cb];
#pragma unroll
            for (int mt = 0; mt < 4; ++mt)
#pragma unroll
                for (int i = 0; i < 4; ++i) {
                    int rl = mt * 16 + rq + i;
                    int byte = (rl * 1024 + (ncol + cb) * 2) ^ ((rl & 7) << 4);
                    *(__bf16*)(hb + byte) = (__bf16)fmaxf(acc2[mt][nt][i] + bb, 0.f);
                }
        }
    }
    __syncthreads();

    // ---- phase 3: out = h2 @ f3w + b3; waves 0..3 -> m-tile w, n-tiles 0..2
    if (w < 4) {
        f32x4 acc3[3];
#pragma unroll
        for (int nt = 0; nt < 3; ++nt) acc3[nt] = (f32x4){0.f, 0.f, 0.f, 0.f};
        const __bf16* b3p = f3P + lane * 8;
#pragma unroll
        for (int ks = 0; ks < 16; ++ks) {
            int rl = w * 16 + cb;
            int byte = (rl * 1024 + (ks * 32 + kc) * 2) ^ ((rl & 7) << 4);
            bf16x8 a3 = *(const bf16x8*)(hb + byte);
#pragma unroll
            for (int nt = 0; nt < 3; ++nt) {
                bf16x8 b = *(const bf16x8*)(b3p + (nt * 16 + ks) * 512);
                acc3[nt] = MFMA16(a3, b, acc3[nt]);
            }
        }
#pragma unroll
        for (int nt = 0; nt < 3; ++nt) {
            int col = nt * 16 + cb;
            if (col < 47) {
                float bb = f3b[col];
                int r = r0 + w * 16 + rq;
#pragma unroll
                for (int i = 0; i < 4; ++i)
                    if (r + i < M) out[(size_t)(r + i) * 47 + col] = acc3[nt][i] + bb;
            }
        }
    }
}

// ------------------------- launch -------------------------------------------

extern "C" void kernel_launch(void* const* d_in, const int* in_sizes, int n_in,
                              void* d_out, int out_size, void* d_ws, size_t ws_size,
                              hipStream_t stream) {
    const float* X        = (const float*)d_in[0];
    const int*   ei       = (const int*)d_in[1];
    const float* emb_w    = (const float*)d_in[2];
    const float* emb_b    = (const float*)d_in[3];
    const float* emb_ln_g = (const float*)d_in[4];
    const float* emb_ln_b = (const float*)d_in[5];
    const float* Wq       = (const float*)d_in[6];
    const float* Wk       = (const float*)d_in[7];
    const float* Wv       = (const float*)d_in[8];
    const float* Wo       = (const float*)d_in[9];
    const float* ln_g     = (const float*)d_in[10];
    const float* ln_b     = (const float*)d_in[11];
    const float* f1w      = (const float*)d_in[12];
    const float* f1b      = (const float*)d_in[13];
    const float* f2w      = (const float*)d_in[14];
    const float* f2b      = (const float*)d_in[15];
    const float* f3w      = (const float*)d_in[16];
    const float* f3b      = (const float*)d_in[17];

    const int N = in_sizes[0] / 256;  // 50000
    const int E = in_sizes[1] / 2;    // 640000
    const int NB = (N + 1023) / 1024;

    // ---- workspace layout
    char* p = (char*)d_ws;
    float* h = (float*)p;            p += (size_t)N * 128 * 4;
    __bf16* hbf = (__bf16*)p;        p += (size_t)N * 128 * 2;
    __bf16* qkv = (__bf16*)p;        p += (size_t)N * 384 * 2;
    __bf16* aggb = (__bf16*)p;       p += (size_t)N * 128 * 2;
    __bf16* embT = (__bf16*)p;       p += 128 * 256 * 2;
    __bf16* qkvT = (__bf16*)p;       p += 3 * 384 * 128 * 2;
    __bf16* woT = (__bf16*)p;        p += 3 * 128 * 128 * 2;
    __bf16* f1T = (__bf16*)p;        p += 512 * 128 * 2;
    __bf16* f2T = (__bf16*)p;        p += 512 * 512 * 2;
    __bf16* f3T = (__bf16*)p;        p += 48 * 512 * 2;
    __bf16* f1P = (__bf16*)p;        p += 8192 * 8 * 2;
    __bf16* f2P = (__bf16*)p;        p += 32768 * 8 * 2;
    __bf16* f3P = (__bf16*)p;        p += 3072 * 8 * 2;
    int* deg = (int*)p;              p += (size_t)N * 4;
    int* cursor = (int*)p;           p += (size_t)N * 4;
    int* row_ptr = (int*)p;          p += (size_t)(N + 1) * 4;
    int* csr_src = (int*)p;          p += (size_t)E * 4;
    int* partials = (int*)p;

    // ---- CSR build
    hipMemsetAsync(deg, 0, (size_t)2 * N * 4, stream);  // zeros deg + cursor
    count_deg<<<(E + 255) / 256, 256, 0, stream>>>(ei, deg, E);
    scan_part<<<NB, 256, 0, stream>>>(deg, partials, N);
    scan_mid<<<1, 64, 0, stream>>>(partials, row_ptr, NB, N);
    scan_final<<<NB, 256, 0, stream>>>(deg, partials, row_ptr, N);
    scatter_edges<<<(E + 255) / 256, 256, 0, stream>>>(ei, row_ptr, cursor, csr_src, E);

    transpose_all<<<576, 256, 0, stream>>>(emb_w, f1w, f2w, f3w, Wq, Wk, Wv, Wo,
                                           embT, f1T, f2T, f3T, qkvT, woT);
    pack_frag<<<172, 256, 0, stream>>>(f1T, f2T, f3T, f1P, f2P, f3P);

    int gwave = (N + 15) / 16;    // 3125 one-wave blocks for gemm_ln
    int gm128 = (N + 127) / 128;  // 391 row panels for gemm_tile

    // ---- embedding: LN(relu(X @ emb_w + emb_b)) -> h (fp32) + hbf
    gemm_ln<256, true><<<gwave, 64, 0, stream>>>(X, embT, emb_b, nullptr,
                                                 emb_ln_g, emb_ln_b, h, hbf, N);

    // ---- layers
    for (int l = 0; l < 3; ++l) {
        gemm_tile<4, 0><<<dim3(3, gm128), 256, 0, stream>>>(
            hbf, qkvT + (size_t)l * 49152, nullptr, qkv, N, 384, 384);
        attn_gat<<<(N + 3) / 4, 256, 0, stream>>>(qkv, row_ptr, csr_src, aggb, N);
        gemm_ln<128, false><<<gwave, 64, 0, stream>>>(aggb, woT + (size_t)l * 16384,
                                                      nullptr, h,
                                                      ln_g + (size_t)l * 128,
                                                      ln_b + (size_t)l * 128, h, hbf, N);
    }

    // ---- FFN head
    ffn_mfma<<<(N + 63) / 64, 512, 0, stream>>>(hbf, f1P, f1b, f2P, f2b, f3P, f3b,
                                                (float*)d_out, N);
}

// Round 14
// 473.228 us; speedup vs baseline: 1.1506x; 1.0409x over previous
//
#include <hip/hip_runtime.h>
#include <hip/hip_bf16.h>
#include <math.h>

// ---------------------------------------------------------------------------
// GraphMemoryNetwork — Round 14: R13 + XCD-bijective swizzle on gemm_tile
// row panels (T1) + s_setprio around ffn MFMA clusters (T5).
// N=50000, E=640000, D_IN=256, D=128, H=8, DH=16, NC=47, L=3
// ---------------------------------------------------------------------------

typedef __bf16 bf16x8 __attribute__((ext_vector_type(8)));
typedef float  f32x4  __attribute__((ext_vector_type(4)));

#define MFMA16(a, b, c) __builtin_amdgcn_mfma_f32_16x16x32_bf16((a), (b), (c), 0, 0, 0)

// async 16B/lane global -> LDS (wave-uniform LDS base + lane*16)
__device__ __forceinline__ void ld_lds16(const __bf16* g, __bf16* l) {
    __builtin_amdgcn_global_load_lds(
        (__attribute__((address_space(1))) void*)g,
        (__attribute__((address_space(3))) void*)l, 16, 0, 0);
}

// bijective XCD chunking (m204): round-robin dispatch -> contiguous chunks
__device__ __forceinline__ int xcd_swz(int orig, int nwg) {
    int q = nwg >> 3, r = nwg & 7;
    int xcd = orig & 7, idx = orig >> 3;
    int base = (xcd < r) ? xcd * (q + 1) : r * (q + 1) + (xcd - r) * q;
    int wg = base + idx;
    return (wg < nwg) ? wg : orig;  // safety (shouldn't trigger)
}

// ------------------------- CSR build ---------------------------------------

__global__ __launch_bounds__(256) void count_deg(const int* __restrict__ ei,
                                                 int* __restrict__ deg, int E) {
    int e = blockIdx.x * 256 + threadIdx.x;
    if (e < E) atomicAdd(&deg[ei[(size_t)E + e]], 1);   // dst = ei[1][e]
}

__global__ __launch_bounds__(256) void scan_part(const int* __restrict__ deg,
                                                 int* __restrict__ partials, int N) {
    int b = blockIdx.x, t = threadIdx.x, lane = t & 63, w = t >> 6;
    int base = b * 1024 + t * 4;
    int4 v = make_int4(0, 0, 0, 0);
    if (base + 3 < N) v = *(const int4*)&deg[base];
    else {
        if (base < N)     v.x = deg[base];
        if (base + 1 < N) v.y = deg[base + 1];
        if (base + 2 < N) v.z = deg[base + 2];
    }
    int s = v.x + v.y + v.z + v.w;
#pragma unroll
    for (int o = 1; o < 64; o <<= 1) s += __shfl_xor(s, o);
    __shared__ int ws[4];
    if (lane == 0) ws[w] = s;
    __syncthreads();
    if (t == 0) partials[b] = ws[0] + ws[1] + ws[2] + ws[3];
}

__global__ __launch_bounds__(64) void scan_mid(int* __restrict__ partials,
                                               int* __restrict__ row_ptr,
                                               int nb, int N) {
    int t = threadIdx.x;
    int v = (t < nb) ? partials[t] : 0;
    int incl = v;
#pragma unroll
    for (int o = 1; o < 64; o <<= 1) {
        int u = __shfl_up(incl, o);
        if (t >= o) incl += u;
    }
    if (t < nb) partials[t] = incl - v;
    if (t == nb - 1) row_ptr[N] = incl;
}

__global__ __launch_bounds__(256) void scan_final(const int* __restrict__ deg,
                                                  const int* __restrict__ partials,
                                                  int* __restrict__ row_ptr, int N) {
    int b = blockIdx.x, t = threadIdx.x, lane = t & 63, w = t >> 6;
    int base = b * 1024 + t * 4;
    int4 v = make_int4(0, 0, 0, 0);
    if (base + 3 < N) v = *(const int4*)&deg[base];
    else {
        if (base < N)     v.x = deg[base];
        if (base + 1 < N) v.y = deg[base + 1];
        if (base + 2 < N) v.z = deg[base + 2];
    }
    int c1 = v.x, c2 = c1 + v.y, c3 = c2 + v.z, c4 = c3 + v.w;
    int s = c4, incl = s;
#pragma unroll
    for (int o = 1; o < 64; o <<= 1) {
        int u = __shfl_up(incl, o);
        if (lane >= o) incl += u;
    }
    int texcl = incl - s;
    __shared__ int ws[4];
    if (lane == 63) ws[w] = incl;
    __syncthreads();
    int woff = 0;
    for (int i = 0; i < w; ++i) woff += ws[i];
    int off = partials[b] + woff + texcl;
    if (base < N)     row_ptr[base]     = off;
    if (base + 1 < N) row_ptr[base + 1] = off + c1;
    if (base + 2 < N) row_ptr[base + 2] = off + c2;
    if (base + 3 < N) row_ptr[base + 3] = off + c3;
}

__global__ __launch_bounds__(256) void scatter_edges(const int* __restrict__ ei,
                                                     const int* __restrict__ row_ptr,
                                                     int* __restrict__ cursor,
                                                     int* __restrict__ csr_src, int E) {
    int e = blockIdx.x * 256 + threadIdx.x;
    if (e < E) {
        int d = ei[(size_t)E + e];
        int pos = row_ptr[d] + atomicAdd(&cursor[d], 1);
        csr_src[pos] = ei[e];
    }
}

// ------------------------- batched weight transpose -------------------------

__global__ __launch_bounds__(256) void transpose_all(
    const float* __restrict__ emb_w, const float* __restrict__ f1w,
    const float* __restrict__ f2w, const float* __restrict__ f3w,
    const float* __restrict__ Wq, const float* __restrict__ Wk,
    const float* __restrict__ Wv, const float* __restrict__ Wo,
    __bf16* __restrict__ embT, __bf16* __restrict__ f1T,
    __bf16* __restrict__ f2T, __bf16* __restrict__ f3T,
    __bf16* __restrict__ qkvT, __bf16* __restrict__ woT) {
    __shared__ float tile[32][33];
    int t = blockIdx.x;
    const float* src; __bf16* dst; int K, Nin, Npad, nxt;
    if (t < 32)       { src = emb_w; dst = embT; K = 256; Nin = 128; Npad = 128; nxt = 4; }
    else if (t < 96)  { t -= 32;  src = f1w; dst = f1T; K = 128; Nin = 512; Npad = 512; nxt = 16; }
    else if (t < 352) { t -= 96;  src = f2w; dst = f2T; K = 512; Nin = 512; Npad = 512; nxt = 16; }
    else if (t < 384) { t -= 352; src = f3w; dst = f3T; K = 512; Nin = 47;  Npad = 48;  nxt = 2; }
    else {
        t -= 384;
        int mat = t >> 4; t &= 15;
        int l = mat >> 2, m = mat & 3;
        src = (m == 0 ? Wq : m == 1 ? Wk : m == 2 ? Wv : Wo) + (size_t)l * 16384;
        dst = (m < 3) ? qkvT + (size_t)l * 49152 + (size_t)m * 16384
                      : woT + (size_t)l * 16384;
        K = 128; Nin = 128; Npad = 128; nxt = 4;
    }
    int n0 = (t % nxt) * 32, k0 = (t / nxt) * 32;
    int tx = threadIdx.x & 31, ty = threadIdx.x >> 5;
#pragma unroll
    for (int i = 0; i < 32; i += 8) {
        int k = k0 + ty + i, n = n0 + tx;
        tile[ty + i][tx] = (k < K && n < Nin) ? src[(size_t)k * Nin + n] : 0.f;
    }
    __syncthreads();
#pragma unroll
    for (int i = 0; i < 32; i += 8) {
        int n = n0 + ty + i, k = k0 + tx;
        if (n < Npad && k < K) dst[(size_t)n * K + k] = (__bf16)tile[tx][ty + i];
    }
}

// ------------------------- fragment packer ----------------------------------

__global__ __launch_bounds__(256) void pack_frag(const __bf16* __restrict__ f1T,
                                                 const __bf16* __restrict__ f2T,
                                                 const __bf16* __restrict__ f3T,
                                                 __bf16* __restrict__ f1P,
                                                 __bf16* __restrict__ f2P,
                                                 __bf16* __restrict__ f3P) {
    int idx = blockIdx.x * 256 + threadIdx.x;
    const __bf16* src; __bf16* dst; int K, base;
    if (idx < 8192)        { src = f1T; dst = f1P; K = 128; base = idx; }
    else if (idx < 40960)  { src = f2T; dst = f2P; K = 512; base = idx - 8192; }
    else if (idx < 44032)  { src = f3T; dst = f3P; K = 512; base = idx - 40960; }
    else return;
    int lane = base & 63;
    int nks = K / 32;
    int ks = (base >> 6) % nks;
    int tile = base / (64 * nks);
    int cb = lane & 15, kcg = lane >> 4;
    bf16x8 v = *(const bf16x8*)&src[(size_t)(tile * 16 + cb) * K + ks * 32 + kcg * 8];
    *(bf16x8*)&dst[(size_t)base * 8] = v;
}

// ------------------------- block-tiled MFMA GEMM (async LDS staging) --------
// 128x128 tile, BK=32, 4 waves. Row-panel index XCD-swizzled so the 3-4
// col-tiles of one panel land on the same XCD -> A panel L2 reuse.

template <int NK, int EPI>
__global__ __launch_bounds__(256) void gemm_tile(const __bf16* __restrict__ A,
                                                 const __bf16* __restrict__ BT,
                                                 const float* __restrict__ bias,
                                                 void* __restrict__ Cv,
                                                 int M, int ldc, int ncols) {
    constexpr int K = NK * 32;
    __shared__ __bf16 As[2][4096];
    __shared__ __bf16 Bs[2][4096];
    int t = threadIdx.x, w = t >> 6, lane = t & 63;
    int cb = lane & 15, rq = (lane >> 4) * 4;
    int n0 = blockIdx.x * 128;
    int m0 = xcd_swz(blockIdx.y, gridDim.y) * 128;

    int sr = lane & 15;
    int sk = (lane >> 4) * 8;
    int ar0 = m0 + (2 * w) * 16 + sr;     if (ar0 >= M) ar0 = M - 1;
    int ar1 = m0 + (2 * w + 1) * 16 + sr; if (ar1 >= M) ar1 = M - 1;
    const __bf16* ag0 = A + (size_t)ar0 * K + sk;
    const __bf16* ag1 = A + (size_t)ar1 * K + sk;
    const __bf16* bg0 = BT + (size_t)(n0 + (2 * w) * 16 + sr) * K + sk;
    const __bf16* bg1 = BT + (size_t)(n0 + (2 * w + 1) * 16 + sr) * K + sk;
    __bf16* la0[2] = { &As[0][(2 * w) * 512],     &As[1][(2 * w) * 512] };
    __bf16* la1[2] = { &As[0][(2 * w + 1) * 512], &As[1][(2 * w + 1) * 512] };
    __bf16* lb0[2] = { &Bs[0][(2 * w) * 512],     &Bs[1][(2 * w) * 512] };
    __bf16* lb1[2] = { &Bs[0][(2 * w + 1) * 512], &Bs[1][(2 * w + 1) * 512] };

    ld_lds16(ag0, la0[0]);
    ld_lds16(ag1, la1[0]);
    ld_lds16(bg0, lb0[0]);
    ld_lds16(bg1, lb1[0]);
    __syncthreads();

    int wm = w >> 1, wn = w & 1;
    f32x4 acc[4][4];
#pragma unroll
    for (int i = 0; i < 4; ++i)
#pragma unroll
        for (int j = 0; j < 4; ++j) acc[i][j] = (f32x4){0.f, 0.f, 0.f, 0.f};

#pragma unroll
    for (int ks = 0; ks < NK; ++ks) {
        int cur = ks & 1;
        if (ks + 1 < NK) {
            int nxt = cur ^ 1;
            ld_lds16(ag0 + (ks + 1) * 32, la0[nxt]);
            ld_lds16(ag1 + (ks + 1) * 32, la1[nxt]);
            ld_lds16(bg0 + (ks + 1) * 32, lb0[nxt]);
            ld_lds16(bg1 + (ks + 1) * 32, lb1[nxt]);
        }
        bf16x8 af[4], bfr[4];
#pragma unroll
        for (int i = 0; i < 4; ++i)
            af[i] = *(const bf16x8*)&As[cur][(wm * 4 + i) * 512 + lane * 8];
#pragma unroll
        for (int j = 0; j < 4; ++j)
            bfr[j] = *(const bf16x8*)&Bs[cur][(wn * 4 + j) * 512 + lane * 8];
        __builtin_amdgcn_s_setprio(1);
#pragma unroll
        for (int j = 0; j < 4; ++j)
#pragma unroll
            for (int i = 0; i < 4; ++i)
                acc[i][j] = MFMA16(af[i], bfr[j], acc[i][j]);
        __builtin_amdgcn_s_setprio(0);
        __syncthreads();
    }

#pragma unroll
    for (int j = 0; j < 4; ++j) {
        int col = n0 + (wn * 4 + j) * 16 + cb;
        float bb = 0.f;
        if (EPI >= 1 && col < ncols) bb = bias[col];
#pragma unroll
        for (int i = 0; i < 4; ++i) {
#pragma unroll
            for (int ii = 0; ii < 4; ++ii) {
                int row = m0 + (wm * 4 + i) * 16 + rq + ii;
                if (row >= M) continue;
                float v = acc[i][j][ii] + bb;
                if (EPI == 0) {
                    ((__bf16*)Cv)[(size_t)row * ldc + col] = (__bf16)v;
                } else if (EPI == 1) {
                    ((__bf16*)Cv)[(size_t)row * ldc + col] = (__bf16)fmaxf(v, 0.f);
                } else {
                    if (col < ncols)
                        ((float*)Cv)[(size_t)row * ldc + col] = v;
                }
            }
        }
    }
}

// ------------------------- MFMA GEMM + fused LayerNorm (1 wave / block) -----

template <int K, bool EMB>
__global__ __launch_bounds__(64) void gemm_ln(const void* __restrict__ Av,
                                              const __bf16* __restrict__ BT,
                                              const float* __restrict__ bias,
                                              const float* resid,
                                              const float* __restrict__ g,
                                              const float* __restrict__ beta,
                                              float* hout, __bf16* __restrict__ hbf,
                                              int M) {
    int wid = blockIdx.x;
    int lane = threadIdx.x;
    int m0 = wid * 16;
    if (m0 >= M) return;
    constexpr int KS = K / 32;
    int cb = lane & 15;
    int kc = (lane >> 4) * 8;
    int rq = (lane >> 4) * 4;
    int arow = m0 + cb;
    if (arow >= M) arow = M - 1;

    bf16x8 a[KS];
    if constexpr (EMB) {
        const float* A = (const float*)Av;
#pragma unroll
        for (int ks = 0; ks < KS; ++ks) {
            float4 u0 = *(const float4*)&A[(size_t)arow * K + ks * 32 + kc];
            float4 u1 = *(const float4*)&A[(size_t)arow * K + ks * 32 + kc + 4];
            bf16x8 av;
            av[0] = (__bf16)u0.x; av[1] = (__bf16)u0.y; av[2] = (__bf16)u0.z; av[3] = (__bf16)u0.w;
            av[4] = (__bf16)u1.x; av[5] = (__bf16)u1.y; av[6] = (__bf16)u1.z; av[7] = (__bf16)u1.w;
            a[ks] = av;
        }
    } else {
        const __bf16* A = (const __bf16*)Av;
#pragma unroll
        for (int ks = 0; ks < KS; ++ks)
            a[ks] = *(const bf16x8*)&A[(size_t)arow * K + ks * 32 + kc];
    }

    const __bf16* bbase = &BT[(size_t)cb * K + kc];
    bf16x8 bA[KS], bB[KS];
#pragma unroll
    for (int ks = 0; ks < KS; ++ks) bA[ks] = *(const bf16x8*)(bbase + ks * 32);

    f32x4 acc[8];
#pragma unroll
    for (int nt = 0; nt < 8; ++nt) acc[nt] = (f32x4){0.f, 0.f, 0.f, 0.f};

#pragma unroll
    for (int nt = 0; nt < 8; nt += 2) {
#pragma unroll
        for (int ks = 0; ks < KS; ++ks)
            bB[ks] = *(const bf16x8*)(bbase + (size_t)(nt + 1) * 16 * K + ks * 32);
#pragma unroll
        for (int ks = 0; ks < KS; ++ks)
            acc[nt] = MFMA16(a[ks], bA[ks], acc[nt]);
        if (nt + 2 < 8) {
#pragma unroll
            for (int ks = 0; ks < KS; ++ks)
                bA[ks] = *(const bf16x8*)(bbase + (size_t)(nt + 2) * 16 * K + ks * 32);
        }
#pragma unroll
        for (int ks = 0; ks < KS; ++ks)
            acc[nt + 1] = MFMA16(a[ks], bB[ks], acc[nt + 1]);
    }

#pragma unroll
    for (int nt = 0; nt < 8; ++nt) {
        int col = nt * 16 + cb;
        float bb = EMB ? bias[col] : 0.f;
#pragma unroll
        for (int i = 0; i < 4; ++i) {
            float v = acc[nt][i];
            if (EMB) {
                v = fmaxf(v + bb, 0.f);
            } else {
                int row = m0 + rq + i;
                if (row >= M) row = M - 1;
                v += resid[(size_t)row * 128 + col];
            }
            acc[nt][i] = v;
        }
    }

    float s[4] = {0.f, 0.f, 0.f, 0.f}, qs[4] = {0.f, 0.f, 0.f, 0.f};
#pragma unroll
    for (int nt = 0; nt < 8; ++nt)
#pragma unroll
        for (int i = 0; i < 4; ++i) {
            float v = acc[nt][i];
            s[i] += v;
            qs[i] += v * v;
        }
#pragma unroll
    for (int i = 0; i < 4; ++i)
#pragma unroll
        for (int o = 1; o < 16; o <<= 1) {
            s[i] += __shfl_xor(s[i], o);
            qs[i] += __shfl_xor(qs[i], o);
        }
    float mu[4], rstd[4];
#pragma unroll
    for (int i = 0; i < 4; ++i) {
        mu[i] = s[i] * (1.f / 128.f);
        float var = qs[i] * (1.f / 128.f) - mu[i] * mu[i];
        rstd[i] = rsqrtf(var + 1e-5f);
    }

#pragma unroll
    for (int nt = 0; nt < 8; ++nt) {
        int col = nt * 16 + cb;
        float gv = g[col], bv = beta[col];
#pragma unroll
        for (int i = 0; i < 4; ++i) {
            int row = m0 + rq + i;
            if (row >= M) continue;
            float y = (acc[nt][i] - mu[i]) * rstd[i] * gv + bv;
            size_t idx = (size_t)row * 128 + col;
            hout[idx] = y;
            hbf[idx] = (__bf16)y;
        }
    }
}

// ------------------------- attention (pipelined gathers) --------------------

__global__ __launch_bounds__(256) void attn_gat(const __bf16* __restrict__ qkv,
                                                const int* __restrict__ row_ptr,
                                                const int* __restrict__ csr_src,
                                                __bf16* __restrict__ agg, int N) {
    int wave = threadIdx.x >> 6;
    int lane = threadIdx.x & 63;
    int n = blockIdx.x * 4 + wave;
    if (n >= N) return;
    int j = lane >> 4, q16 = lane & 15, c0 = q16 * 8;
    const float scale = 0.25f;  // 1/sqrt(16)

    int e0 = row_ptr[n], e1 = row_ptr[n + 1];

    bf16x8 qv = *(const bf16x8*)&qkv[(size_t)n * 384 + c0];
    float qf[8];
#pragma unroll
    for (int i = 0; i < 8; ++i) qf[i] = (float)qv[i];

    float m = -3e38f, s = 0.f;
    float acc[8] = {0.f, 0.f, 0.f, 0.f, 0.f, 0.f, 0.f, 0.f};

    if (e0 < e1) {
        int e = e0 + j;
        bool v0 = e < e1;
        int i0 = csr_src[v0 ? e : e0];
        const __bf16* kp0 = &qkv[(size_t)i0 * 384 + 128 + c0];
        bf16x8 k0 = *(const bf16x8*)kp0;
        bf16x8 vv0 = *(const bf16x8*)(kp0 + 128);
        int en = e0 + 4 + j;
        bool v1 = en < e1;
        int i1 = csr_src[v1 ? en : e0];

        for (int base = e0; base < e1; base += 4) {
            bf16x8 k1, vv1;
            if (base + 4 < e1) {
                const __bf16* kp1 = &qkv[(size_t)i1 * 384 + 128 + c0];
                k1 = *(const bf16x8*)kp1;
                vv1 = *(const bf16x8*)(kp1 + 128);
            }
            int e2 = base + 8 + j;
            bool v2 = e2 < e1;
            int i2 = csr_src[v2 ? e2 : e0];

            float d = 0.f;
#pragma unroll
            for (int i = 0; i < 8; ++i) d = fmaf(qf[i], (float)k0[i], d);
            d += __shfl_xor(d, 1);
            float sc = d * scale;
            if (v0) {
                float mn = fmaxf(m, sc);
                float f = __expf(m - mn), p = __expf(sc - mn);
                s = s * f + p;
#pragma unroll
                for (int i = 0; i < 8; ++i) acc[i] = acc[i] * f + p * (float)vv0[i];
                m = mn;
            }
            k0 = k1; vv0 = vv1; v0 = v1;
            i1 = i2; v1 = v2;
        }
    }

#pragma unroll
    for (int off = 16; off <= 32; off <<= 1) {
        float mo_ = __shfl_xor(m, off);
        float so_ = __shfl_xor(s, off);
        float mn = fmaxf(m, mo_);
        float f = __expf(m - mn), fo = __expf(mo_ - mn);
        s = s * f + so_ * fo;
#pragma unroll
        for (int i = 0; i < 8; ++i)
            acc[i] = acc[i] * f + __shfl_xor(acc[i], off) * fo;
        m = mn;
    }

    if (j == 0) {
        float inv = (s > 0.f) ? 1.f / s : 0.f;
        bf16x8 o;
#pragma unroll
        for (int i = 0; i < 8; ++i) o[i] = (__bf16)(acc[i] * inv);
        *(bf16x8*)&agg[(size_t)n * 128 + c0] = o;
    }
}

// ------------------------- FFN head -----------------------------------------
// Block = 512 threads (8 waves), 64 rows. Fragment-packed B. setprio(1)
// around MFMA clusters (T5: 2 blocks/CU at different phases -> arbitration).

__global__ __launch_bounds__(512) void ffn_mfma(const __bf16* __restrict__ hbf,
                                                const __bf16* __restrict__ f1P,
                                                const float* __restrict__ f1b,
                                                const __bf16* __restrict__ f2P,
                                                const float* __restrict__ f2b,
                                                const __bf16* __restrict__ f3P,
                                                const float* __restrict__ f3b,
                                                float* __restrict__ out, int M) {
    __shared__ __bf16 hbuf[64 * 512];  // 64 KB; byte = rl*1024+col*2 ^((rl&7)<<4)
    int w = threadIdx.x >> 6;
    int lane = threadIdx.x & 63;
    int r0 = blockIdx.x * 64;
    int cb = lane & 15;
    int kc = (lane >> 4) * 8;
    int rq = (lane >> 4) * 4;
    char* hb = (char*)hbuf;

    // ---- phase 1: h1 = relu(h @ f1w + b1); NT=4, MT=4, K=128 (NKS=4)
    {
        bf16x8 a1[4][4];
#pragma unroll
        for (int mt = 0; mt < 4; ++mt) {
            int row = r0 + mt * 16 + cb;
            if (row >= M) row = M - 1;
#pragma unroll
            for (int ks = 0; ks < 4; ++ks)
                a1[mt][ks] = *(const bf16x8*)&hbf[(size_t)row * 128 + ks * 32 + kc];
        }
        const __bf16* b1p = f1P + (size_t)(w * 4) * 4 * 512 + lane * 8;
        bf16x8 bA[4], bB[4];
#pragma unroll
        for (int ks = 0; ks < 4; ++ks) bA[ks] = *(const bf16x8*)(b1p + ks * 512);
#pragma unroll
        for (int nt = 0; nt < 4; nt += 2) {
#pragma unroll
            for (int ks = 0; ks < 4; ++ks)
                bB[ks] = *(const bf16x8*)(b1p + ((nt + 1) * 4 + ks) * 512);
            {
                f32x4 acc[4];
#pragma unroll
                for (int mt = 0; mt < 4; ++mt) acc[mt] = (f32x4){0.f, 0.f, 0.f, 0.f};
                __builtin_amdgcn_s_setprio(1);
#pragma unroll
                for (int ks = 0; ks < 4; ++ks)
#pragma unroll
                    for (int mt = 0; mt < 4; ++mt)
                        acc[mt] = MFMA16(a1[mt][ks], bA[ks], acc[mt]);
                __builtin_amdgcn_s_setprio(0);
                int ncol = w * 64 + nt * 16;
                float bb = f1b[ncol + cb];
#pragma unroll
                for (int mt = 0; mt < 4; ++mt)
#pragma unroll
                    for (int i = 0; i < 4; ++i) {
                        int rl = mt * 16 + rq + i;
                        int byte = (rl * 1024 + (ncol + cb) * 2) ^ ((rl & 7) << 4);
                        *(__bf16*)(hb + byte) = (__bf16)fmaxf(acc[mt][i] + bb, 0.f);
                    }
            }
            if (nt + 2 < 4) {
#pragma unroll
                for (int ks = 0; ks < 4; ++ks)
                    bA[ks] = *(const bf16x8*)(b1p + ((nt + 2) * 4 + ks) * 512);
            }
            {
                f32x4 acc[4];
#pragma unroll
                for (int mt = 0; mt < 4; ++mt) acc[mt] = (f32x4){0.f, 0.f, 0.f, 0.f};
                __builtin_amdgcn_s_setprio(1);
#pragma unroll
                for (int ks = 0; ks < 4; ++ks)
#pragma unroll
                    for (int mt = 0; mt < 4; ++mt)
                        acc[mt] = MFMA16(a1[mt][ks], bB[ks], acc[mt]);
                __builtin_amdgcn_s_setprio(0);
                int ncol = w * 64 + (nt + 1) * 16;
                float bb = f1b[ncol + cb];
#pragma unroll
                for (int mt = 0; mt < 4; ++mt)
#pragma unroll
                    for (int i = 0; i < 4; ++i) {
                        int rl = mt * 16 + rq + i;
                        int byte = (rl * 1024 + (ncol + cb) * 2) ^ ((rl & 7) << 4);
                        *(__bf16*)(hb + byte) = (__bf16)fmaxf(acc[mt][i] + bb, 0.f);
                    }
            }
        }
    }
    __syncthreads();

    // ---- phase 2: h2 = relu(h1 @ f2w + b2); K=512 (NKS=16)
    {
        f32x4 acc2[4][4];
#pragma unroll
        for (int mt = 0; mt < 4; ++mt)
#pragma unroll
            for (int nt = 0; nt < 4; ++nt) acc2[mt][nt] = (f32x4){0.f, 0.f, 0.f, 0.f};

        const __bf16* b2p = f2P + (size_t)(w * 4) * 16 * 512 + lane * 8;

        bf16x8 b0[4], b1[4];
#pragma unroll
        for (int nt = 0; nt < 4; ++nt) b0[nt] = *(const bf16x8*)(b2p + nt * 16 * 512);

#pragma unroll
        for (int ks = 0; ks < 16; ks += 2) {
#pragma unroll
            for (int nt = 0; nt < 4; ++nt)
                b1[nt] = *(const bf16x8*)(b2p + (nt * 16 + ks + 1) * 512);
            {
                bf16x8 a2[4];
#pragma unroll
                for (int mt = 0; mt < 4; ++mt) {
                    int rl = mt * 16 + cb;
                    int byte = (rl * 1024 + (ks * 32 + kc) * 2) ^ ((rl & 7) << 4);
                    a2[mt] = *(const bf16x8*)(hb + byte);
                }
                __builtin_amdgcn_s_setprio(1);
#pragma unroll
                for (int nt = 0; nt < 4; ++nt)
#pragma unroll
                    for (int mt = 0; mt < 4; ++mt)
                        acc2[mt][nt] = MFMA16(a2[mt], b0[nt], acc2[mt][nt]);
                __builtin_amdgcn_s_setprio(0);
            }
            if (ks + 2 < 16) {
#pragma unroll
                for (int nt = 0; nt < 4; ++nt)
                    b0[nt] = *(const bf16x8*)(b2p + (nt * 16 + ks + 2) * 512);
            }
            {
                bf16x8 a2[4];
#pragma unroll
                for (int mt = 0; mt < 4; ++mt) {
                    int rl = mt * 16 + cb;
                    int byte = (rl * 1024 + ((ks + 1) * 32 + kc) * 2) ^ ((rl & 7) << 4);
                    a2[mt] = *(const bf16x8*)(hb + byte);
                }
                __builtin_amdgcn_s_setprio(1);
#pragma unroll
                for (int nt = 0; nt < 4; ++nt)
#pragma unroll
                    for (int mt = 0; mt < 4; ++mt)
                        acc2[mt][nt] = MFMA16(a2[mt], b1[nt], acc2[mt][nt]);
                __builtin_amdgcn_s_setprio(0);
            }
        }
        __syncthreads();  // all h1 reads done before overwrite

#pragma unroll
        for (int nt = 0; nt < 4; ++nt) {
            int ncol = w * 64 + nt * 16;
            float bb = f2b[ncol + cb];
#pragma unroll
            for (int mt = 0; mt < 4; ++mt)
#pragma unroll
                for (int i = 0; i < 4; ++i) {
                    int rl = mt * 16 + rq + i;
                    int byte = (rl * 1024 + (ncol + cb) * 2) ^ ((rl & 7) << 4);
                    *(__bf16*)(hb + byte) = (__bf16)fmaxf(acc2[mt][nt][i] + bb, 0.f);
                }
        }
    }
    __syncthreads();

    // ---- phase 3: out = h2 @ f3w + b3; waves 0..3 -> m-tile w, n-tiles 0..2
    if (w < 4) {
        f32x4 acc3[3];
#pragma unroll
        for (int nt = 0; nt < 3; ++nt) acc3[nt] = (f32x4){0.f, 0.f, 0.f, 0.f};
        const __bf16* b3p = f3P + lane * 8;
#pragma unroll
        for (int ks = 0; ks < 16; ++ks) {
            int rl = w * 16 + cb;
            int byte = (rl * 1024 + (ks * 32 + kc) * 2) ^ ((rl & 7) << 4);
            bf16x8 a3 = *(const bf16x8*)(hb + byte);
#pragma unroll
            for (int nt = 0; nt < 3; ++nt) {
                bf16x8 b = *(const bf16x8*)(b3p + (nt * 16 + ks) * 512);
                acc3[nt] = MFMA16(a3, b, acc3[nt]);
            }
        }
#pragma unroll
        for (int nt = 0; nt < 3; ++nt) {
            int col = nt * 16 + cb;
            if (col < 47) {
                float bb = f3b[col];
                int r = r0 + w * 16 + rq;
#pragma unroll
                for (int i = 0; i < 4; ++i)
                    if (r + i < M) out[(size_t)(r + i) * 47 + col] = acc3[nt][i] + bb;
            }
        }
    }
}

// ------------------------- launch -------------------------------------------

extern "C" void kernel_launch(void* const* d_in, const int* in_sizes, int n_in,
                              void* d_out, int out_size, void* d_ws, size_t ws_size,
                              hipStream_t stream) {
    const float* X        = (const float*)d_in[0];
    const int*   ei       = (const int*)d_in[1];
    const float* emb_w    = (const float*)d_in[2];
    const float* emb_b    = (const float*)d_in[3];
    const float* emb_ln_g = (const float*)d_in[4];
    const float* emb_ln_b = (const float*)d_in[5];
    const float* Wq       = (const float*)d_in[6];
    const float* Wk       = (const float*)d_in[7];
    const float* Wv       = (const float*)d_in[8];
    const float* Wo       = (const float*)d_in[9];
    const float* ln_g     = (const float*)d_in[10];
    const float* ln_b     = (const float*)d_in[11];
    const float* f1w      = (const float*)d_in[12];
    const float* f1b      = (const float*)d_in[13];
    const float* f2w      = (const float*)d_in[14];
    const float* f2b      = (const float*)d_in[15];
    const float* f3w      = (const float*)d_in[16];
    const float* f3b      = (const float*)d_in[17];

    const int N = in_sizes[0] / 256;  // 50000
    const int E = in_sizes[1] / 2;    // 640000
    const int NB = (N + 1023) / 1024;

    // ---- workspace layout
    char* p = (char*)d_ws;
    float* h = (float*)p;            p += (size_t)N * 128 * 4;
    __bf16* hbf = (__bf16*)p;        p += (size_t)N * 128 * 2;
    __bf16* qkv = (__bf16*)p;        p += (size_t)N * 384 * 2;
    __bf16* aggb = (__bf16*)p;       p += (size_t)N * 128 * 2;
    __bf16* embT = (__bf16*)p;       p += 128 * 256 * 2;
    __bf16* qkvT = (__bf16*)p;       p += 3 * 384 * 128 * 2;
    __bf16* woT = (__bf16*)p;        p += 3 * 128 * 128 * 2;
    __bf16* f1T = (__bf16*)p;        p += 512 * 128 * 2;
    __bf16* f2T = (__bf16*)p;        p += 512 * 512 * 2;
    __bf16* f3T = (__bf16*)p;        p += 48 * 512 * 2;
    __bf16* f1P = (__bf16*)p;        p += 8192 * 8 * 2;
    __bf16* f2P = (__bf16*)p;        p += 32768 * 8 * 2;
    __bf16* f3P = (__bf16*)p;        p += 3072 * 8 * 2;
    int* deg = (int*)p;              p += (size_t)N * 4;
    int* cursor = (int*)p;           p += (size_t)N * 4;
    int* row_ptr = (int*)p;          p += (size_t)(N + 1) * 4;
    int* csr_src = (int*)p;          p += (size_t)E * 4;
    int* partials = (int*)p;

    // ---- CSR build
    hipMemsetAsync(deg, 0, (size_t)2 * N * 4, stream);  // zeros deg + cursor
    count_deg<<<(E + 255) / 256, 256, 0, stream>>>(ei, deg, E);
    scan_part<<<NB, 256, 0, stream>>>(deg, partials, N);
    scan_mid<<<1, 64, 0, stream>>>(partials, row_ptr, NB, N);
    scan_final<<<NB, 256, 0, stream>>>(deg, partials, row_ptr, N);
    scatter_edges<<<(E + 255) / 256, 256, 0, stream>>>(ei, row_ptr, cursor, csr_src, E);

    transpose_all<<<576, 256, 0, stream>>>(emb_w, f1w, f2w, f3w, Wq, Wk, Wv, Wo,
                                           embT, f1T, f2T, f3T, qkvT, woT);
    pack_frag<<<172, 256, 0, stream>>>(f1T, f2T, f3T, f1P, f2P, f3P);

    int gwave = (N + 15) / 16;    // 3125 one-wave blocks for gemm_ln
    int gm128 = (N + 127) / 128;  // 391 row panels for gemm_tile

    // ---- embedding: LN(relu(X @ emb_w + emb_b)) -> h (fp32) + hbf
    gemm_ln<256, true><<<gwave, 64, 0, stream>>>(X, embT, emb_b, nullptr,
                                                 emb_ln_g, emb_ln_b, h, hbf, N);

    // ---- layers
    for (int l = 0; l < 3; ++l) {
        gemm_tile<4, 0><<<dim3(3, gm128), 256, 0, stream>>>(
            hbf, qkvT + (size_t)l * 49152, nullptr, qkv, N, 384, 384);
        attn_gat<<<(N + 3) / 4, 256, 0, stream>>>(qkv, row_ptr, csr_src, aggb, N);
        gemm_ln<128, false><<<gwave, 64, 0, stream>>>(aggb, woT + (size_t)l * 16384,
                                                      nullptr, h,
                                                      ln_g + (size_t)l * 128,
                                                      ln_b + (size_t)l * 128, h, hbf, N);
    }

    // ---- FFN head
    ffn_mfma<<<(N + 63) / 64, 512, 0, stream>>>(hbf, f1P, f1b, f2P, f2b, f3P, f3b,
                                                (float*)d_out, N);
}

// Round 15
// 436.481 us; speedup vs baseline: 1.2475x; 1.0842x over previous
//
#include <hip/hip_runtime.h>
#include <hip/hip_bf16.h>
#include <math.h>

// ---------------------------------------------------------------------------
// GraphMemoryNetwork — Round 15: fragment-packed B for gemm_ln (emb/wo) +
// setprio in gemm_ln. R14 base otherwise.
// N=50000, E=640000, D_IN=256, D=128, H=8, DH=16, NC=47, L=3
// ---------------------------------------------------------------------------

typedef __bf16 bf16x8 __attribute__((ext_vector_type(8)));
typedef float  f32x4  __attribute__((ext_vector_type(4)));

#define MFMA16(a, b, c) __builtin_amdgcn_mfma_f32_16x16x32_bf16((a), (b), (c), 0, 0, 0)

// async 16B/lane global -> LDS (wave-uniform LDS base + lane*16)
__device__ __forceinline__ void ld_lds16(const __bf16* g, __bf16* l) {
    __builtin_amdgcn_global_load_lds(
        (__attribute__((address_space(1))) void*)g,
        (__attribute__((address_space(3))) void*)l, 16, 0, 0);
}

// bijective XCD chunking (m204)
__device__ __forceinline__ int xcd_swz(int orig, int nwg) {
    int q = nwg >> 3, r = nwg & 7;
    int xcd = orig & 7, idx = orig >> 3;
    int base = (xcd < r) ? xcd * (q + 1) : r * (q + 1) + (xcd - r) * q;
    int wg = base + idx;
    return (wg < nwg) ? wg : orig;
}

// ------------------------- CSR build ---------------------------------------

__global__ __launch_bounds__(256) void count_deg(const int* __restrict__ ei,
                                                 int* __restrict__ deg, int E) {
    int e = blockIdx.x * 256 + threadIdx.x;
    if (e < E) atomicAdd(&deg[ei[(size_t)E + e]], 1);   // dst = ei[1][e]
}

__global__ __launch_bounds__(256) void scan_part(const int* __restrict__ deg,
                                                 int* __restrict__ partials, int N) {
    int b = blockIdx.x, t = threadIdx.x, lane = t & 63, w = t >> 6;
    int base = b * 1024 + t * 4;
    int4 v = make_int4(0, 0, 0, 0);
    if (base + 3 < N) v = *(const int4*)&deg[base];
    else {
        if (base < N)     v.x = deg[base];
        if (base + 1 < N) v.y = deg[base + 1];
        if (base + 2 < N) v.z = deg[base + 2];
    }
    int s = v.x + v.y + v.z + v.w;
#pragma unroll
    for (int o = 1; o < 64; o <<= 1) s += __shfl_xor(s, o);
    __shared__ int ws[4];
    if (lane == 0) ws[w] = s;
    __syncthreads();
    if (t == 0) partials[b] = ws[0] + ws[1] + ws[2] + ws[3];
}

__global__ __launch_bounds__(64) void scan_mid(int* __restrict__ partials,
                                               int* __restrict__ row_ptr,
                                               int nb, int N) {
    int t = threadIdx.x;
    int v = (t < nb) ? partials[t] : 0;
    int incl = v;
#pragma unroll
    for (int o = 1; o < 64; o <<= 1) {
        int u = __shfl_up(incl, o);
        if (t >= o) incl += u;
    }
    if (t < nb) partials[t] = incl - v;
    if (t == nb - 1) row_ptr[N] = incl;
}

__global__ __launch_bounds__(256) void scan_final(const int* __restrict__ deg,
                                                  const int* __restrict__ partials,
                                                  int* __restrict__ row_ptr, int N) {
    int b = blockIdx.x, t = threadIdx.x, lane = t & 63, w = t >> 6;
    int base = b * 1024 + t * 4;
    int4 v = make_int4(0, 0, 0, 0);
    if (base + 3 < N) v = *(const int4*)&deg[base];
    else {
        if (base < N)     v.x = deg[base];
        if (base + 1 < N) v.y = deg[base + 1];
        if (base + 2 < N) v.z = deg[base + 2];
    }
    int c1 = v.x, c2 = c1 + v.y, c3 = c2 + v.z, c4 = c3 + v.w;
    int s = c4, incl = s;
#pragma unroll
    for (int o = 1; o < 64; o <<= 1) {
        int u = __shfl_up(incl, o);
        if (lane >= o) incl += u;
    }
    int texcl = incl - s;
    __shared__ int ws[4];
    if (lane == 63) ws[w] = incl;
    __syncthreads();
    int woff = 0;
    for (int i = 0; i < w; ++i) woff += ws[i];
    int off = partials[b] + woff + texcl;
    if (base < N)     row_ptr[base]     = off;
    if (base + 1 < N) row_ptr[base + 1] = off + c1;
    if (base + 2 < N) row_ptr[base + 2] = off + c2;
    if (base + 3 < N) row_ptr[base + 3] = off + c3;
}

__global__ __launch_bounds__(256) void scatter_edges(const int* __restrict__ ei,
                                                     const int* __restrict__ row_ptr,
                                                     int* __restrict__ cursor,
                                                     int* __restrict__ csr_src, int E) {
    int e = blockIdx.x * 256 + threadIdx.x;
    if (e < E) {
        int d = ei[(size_t)E + e];
        int pos = row_ptr[d] + atomicAdd(&cursor[d], 1);
        csr_src[pos] = ei[e];
    }
}

// ------------------------- batched weight transpose -------------------------

__global__ __launch_bounds__(256) void transpose_all(
    const float* __restrict__ emb_w, const float* __restrict__ f1w,
    const float* __restrict__ f2w, const float* __restrict__ f3w,
    const float* __restrict__ Wq, const float* __restrict__ Wk,
    const float* __restrict__ Wv, const float* __restrict__ Wo,
    __bf16* __restrict__ embT, __bf16* __restrict__ f1T,
    __bf16* __restrict__ f2T, __bf16* __restrict__ f3T,
    __bf16* __restrict__ qkvT, __bf16* __restrict__ woT) {
    __shared__ float tile[32][33];
    int t = blockIdx.x;
    const float* src; __bf16* dst; int K, Nin, Npad, nxt;
    if (t < 32)       { src = emb_w; dst = embT; K = 256; Nin = 128; Npad = 128; nxt = 4; }
    else if (t < 96)  { t -= 32;  src = f1w; dst = f1T; K = 128; Nin = 512; Npad = 512; nxt = 16; }
    else if (t < 352) { t -= 96;  src = f2w; dst = f2T; K = 512; Nin = 512; Npad = 512; nxt = 16; }
    else if (t < 384) { t -= 352; src = f3w; dst = f3T; K = 512; Nin = 47;  Npad = 48;  nxt = 2; }
    else {
        t -= 384;
        int mat = t >> 4; t &= 15;
        int l = mat >> 2, m = mat & 3;
        src = (m == 0 ? Wq : m == 1 ? Wk : m == 2 ? Wv : Wo) + (size_t)l * 16384;
        dst = (m < 3) ? qkvT + (size_t)l * 49152 + (size_t)m * 16384
                      : woT + (size_t)l * 16384;
        K = 128; Nin = 128; Npad = 128; nxt = 4;
    }
    int n0 = (t % nxt) * 32, k0 = (t / nxt) * 32;
    int tx = threadIdx.x & 31, ty = threadIdx.x >> 5;
#pragma unroll
    for (int i = 0; i < 32; i += 8) {
        int k = k0 + ty + i, n = n0 + tx;
        tile[ty + i][tx] = (k < K && n < Nin) ? src[(size_t)k * Nin + n] : 0.f;
    }
    __syncthreads();
#pragma unroll
    for (int i = 0; i < 32; i += 8) {
        int n = n0 + ty + i, k = k0 + tx;
        if (n < Npad && k < K) dst[(size_t)n * K + k] = (__bf16)tile[tx][ty + i];
    }
}

// ------------------------- fragment packer ----------------------------------
// P[(tile*NKS + ks)*64 + lane]*8 = BT[(tile*16 + (lane&15))*K + ks*32 +
// (lane>>4)*8 ..]. f1: 8192 | f2: 32768 | f3: 3072 | emb: 4096 (8 tiles,
// NKS=8) | wo: 6144 (24 global tiles over 3 layers, NKS=4). Total 54272.

__global__ __launch_bounds__(256) void pack_frag(const __bf16* __restrict__ f1T,
                                                 const __bf16* __restrict__ f2T,
                                                 const __bf16* __restrict__ f3T,
                                                 const __bf16* __restrict__ embT,
                                                 const __bf16* __restrict__ woT,
                                                 __bf16* __restrict__ f1P,
                                                 __bf16* __restrict__ f2P,
                                                 __bf16* __restrict__ f3P,
                                                 __bf16* __restrict__ embP,
                                                 __bf16* __restrict__ woP) {
    int idx = blockIdx.x * 256 + threadIdx.x;
    const __bf16* src; __bf16* dst; int K, base;
    if (idx < 8192)        { src = f1T;  dst = f1P;  K = 128; base = idx; }
    else if (idx < 40960)  { src = f2T;  dst = f2P;  K = 512; base = idx - 8192; }
    else if (idx < 44032)  { src = f3T;  dst = f3P;  K = 512; base = idx - 40960; }
    else if (idx < 48128)  { src = embT; dst = embP; K = 256; base = idx - 44032; }
    else if (idx < 54272)  { src = woT;  dst = woP;  K = 128; base = idx - 48128; }
    else return;
    int lane = base & 63;
    int nks = K / 32;
    int ks = (base >> 6) % nks;
    int tile = base / (64 * nks);
    int cb = lane & 15, kcg = lane >> 4;
    bf16x8 v = *(const bf16x8*)&src[(size_t)(tile * 16 + cb) * K + ks * 32 + kcg * 8];
    *(bf16x8*)&dst[(size_t)base * 8] = v;
}

// ------------------------- block-tiled MFMA GEMM (async LDS staging) --------

template <int NK, int EPI>
__global__ __launch_bounds__(256) void gemm_tile(const __bf16* __restrict__ A,
                                                 const __bf16* __restrict__ BT,
                                                 const float* __restrict__ bias,
                                                 void* __restrict__ Cv,
                                                 int M, int ldc, int ncols) {
    constexpr int K = NK * 32;
    __shared__ __bf16 As[2][4096];
    __shared__ __bf16 Bs[2][4096];
    int t = threadIdx.x, w = t >> 6, lane = t & 63;
    int cb = lane & 15, rq = (lane >> 4) * 4;
    int n0 = blockIdx.x * 128;
    int m0 = xcd_swz(blockIdx.y, gridDim.y) * 128;

    int sr = lane & 15;
    int sk = (lane >> 4) * 8;
    int ar0 = m0 + (2 * w) * 16 + sr;     if (ar0 >= M) ar0 = M - 1;
    int ar1 = m0 + (2 * w + 1) * 16 + sr; if (ar1 >= M) ar1 = M - 1;
    const __bf16* ag0 = A + (size_t)ar0 * K + sk;
    const __bf16* ag1 = A + (size_t)ar1 * K + sk;
    const __bf16* bg0 = BT + (size_t)(n0 + (2 * w) * 16 + sr) * K + sk;
    const __bf16* bg1 = BT + (size_t)(n0 + (2 * w + 1) * 16 + sr) * K + sk;
    __bf16* la0[2] = { &As[0][(2 * w) * 512],     &As[1][(2 * w) * 512] };
    __bf16* la1[2] = { &As[0][(2 * w + 1) * 512], &As[1][(2 * w + 1) * 512] };
    __bf16* lb0[2] = { &Bs[0][(2 * w) * 512],     &Bs[1][(2 * w) * 512] };
    __bf16* lb1[2] = { &Bs[0][(2 * w + 1) * 512], &Bs[1][(2 * w + 1) * 512] };

    ld_lds16(ag0, la0[0]);
    ld_lds16(ag1, la1[0]);
    ld_lds16(bg0, lb0[0]);
    ld_lds16(bg1, lb1[0]);
    __syncthreads();

    int wm = w >> 1, wn = w & 1;
    f32x4 acc[4][4];
#pragma unroll
    for (int i = 0; i < 4; ++i)
#pragma unroll
        for (int j = 0; j < 4; ++j) acc[i][j] = (f32x4){0.f, 0.f, 0.f, 0.f};

#pragma unroll
    for (int ks = 0; ks < NK; ++ks) {
        int cur = ks & 1;
        if (ks + 1 < NK) {
            int nxt = cur ^ 1;
            ld_lds16(ag0 + (ks + 1) * 32, la0[nxt]);
            ld_lds16(ag1 + (ks + 1) * 32, la1[nxt]);
            ld_lds16(bg0 + (ks + 1) * 32, lb0[nxt]);
            ld_lds16(bg1 + (ks + 1) * 32, lb1[nxt]);
        }
        bf16x8 af[4], bfr[4];
#pragma unroll
        for (int i = 0; i < 4; ++i)
            af[i] = *(const bf16x8*)&As[cur][(wm * 4 + i) * 512 + lane * 8];
#pragma unroll
        for (int j = 0; j < 4; ++j)
            bfr[j] = *(const bf16x8*)&Bs[cur][(wn * 4 + j) * 512 + lane * 8];
        __builtin_amdgcn_s_setprio(1);
#pragma unroll
        for (int j = 0; j < 4; ++j)
#pragma unroll
            for (int i = 0; i < 4; ++i)
                acc[i][j] = MFMA16(af[i], bfr[j], acc[i][j]);
        __builtin_amdgcn_s_setprio(0);
        __syncthreads();
    }

#pragma unroll
    for (int j = 0; j < 4; ++j) {
        int col = n0 + (wn * 4 + j) * 16 + cb;
        float bb = 0.f;
        if (EPI >= 1 && col < ncols) bb = bias[col];
#pragma unroll
        for (int i = 0; i < 4; ++i) {
#pragma unroll
            for (int ii = 0; ii < 4; ++ii) {
                int row = m0 + (wm * 4 + i) * 16 + rq + ii;
                if (row >= M) continue;
                float v = acc[i][j][ii] + bb;
                if (EPI == 0) {
                    ((__bf16*)Cv)[(size_t)row * ldc + col] = (__bf16)v;
                } else if (EPI == 1) {
                    ((__bf16*)Cv)[(size_t)row * ldc + col] = (__bf16)fmaxf(v, 0.f);
                } else {
                    if (col < ncols)
                        ((float*)Cv)[(size_t)row * ldc + col] = v;
                }
            }
        }
    }
}

// ------------------------- MFMA GEMM + fused LayerNorm (1 wave / block) -----
// B from fragment-packed weights: frag (nt, ks) at BP + ((nt*KS+ks)*64+lane)*8
// -> each load is part of a contiguous 1KB wave-block (coalesced, no
// over-fetch).

template <int K, bool EMB>
__global__ __launch_bounds__(64) void gemm_ln(const void* __restrict__ Av,
                                              const __bf16* __restrict__ BP,
                                              const float* __restrict__ bias,
                                              const float* resid,
                                              const float* __restrict__ g,
                                              const float* __restrict__ beta,
                                              float* hout, __bf16* __restrict__ hbf,
                                              int M) {
    int wid = blockIdx.x;
    int lane = threadIdx.x;
    int m0 = wid * 16;
    if (m0 >= M) return;
    constexpr int KS = K / 32;
    int cb = lane & 15;
    int kc = (lane >> 4) * 8;
    int rq = (lane >> 4) * 4;
    int arow = m0 + cb;
    if (arow >= M) arow = M - 1;

    bf16x8 a[KS];
    if constexpr (EMB) {
        const float* A = (const float*)Av;
#pragma unroll
        for (int ks = 0; ks < KS; ++ks) {
            float4 u0 = *(const float4*)&A[(size_t)arow * K + ks * 32 + kc];
            float4 u1 = *(const float4*)&A[(size_t)arow * K + ks * 32 + kc + 4];
            bf16x8 av;
            av[0] = (__bf16)u0.x; av[1] = (__bf16)u0.y; av[2] = (__bf16)u0.z; av[3] = (__bf16)u0.w;
            av[4] = (__bf16)u1.x; av[5] = (__bf16)u1.y; av[6] = (__bf16)u1.z; av[7] = (__bf16)u1.w;
            a[ks] = av;
        }
    } else {
        const __bf16* A = (const __bf16*)Av;
#pragma unroll
        for (int ks = 0; ks < KS; ++ks)
            a[ks] = *(const bf16x8*)&A[(size_t)arow * K + ks * 32 + kc];
    }

    const __bf16* bp = BP + lane * 8;
    bf16x8 bA[KS], bB[KS];
#pragma unroll
    for (int ks = 0; ks < KS; ++ks)
        bA[ks] = *(const bf16x8*)(bp + (size_t)ks * 512);

    f32x4 acc[8];
#pragma unroll
    for (int nt = 0; nt < 8; ++nt) acc[nt] = (f32x4){0.f, 0.f, 0.f, 0.f};

#pragma unroll
    for (int nt = 0; nt < 8; nt += 2) {
#pragma unroll
        for (int ks = 0; ks < KS; ++ks)
            bB[ks] = *(const bf16x8*)(bp + (size_t)((nt + 1) * KS + ks) * 512);
        __builtin_amdgcn_s_setprio(1);
#pragma unroll
        for (int ks = 0; ks < KS; ++ks)
            acc[nt] = MFMA16(a[ks], bA[ks], acc[nt]);
        __builtin_amdgcn_s_setprio(0);
        if (nt + 2 < 8) {
#pragma unroll
            for (int ks = 0; ks < KS; ++ks)
                bA[ks] = *(const bf16x8*)(bp + (size_t)((nt + 2) * KS + ks) * 512);
        }
        __builtin_amdgcn_s_setprio(1);
#pragma unroll
        for (int ks = 0; ks < KS; ++ks)
            acc[nt + 1] = MFMA16(a[ks], bB[ks], acc[nt + 1]);
        __builtin_amdgcn_s_setprio(0);
    }

#pragma unroll
    for (int nt = 0; nt < 8; ++nt) {
        int col = nt * 16 + cb;
        float bb = EMB ? bias[col] : 0.f;
#pragma unroll
        for (int i = 0; i < 4; ++i) {
            float v = acc[nt][i];
            if (EMB) {
                v = fmaxf(v + bb, 0.f);
            } else {
                int row = m0 + rq + i;
                if (row >= M) row = M - 1;
                v += resid[(size_t)row * 128 + col];
            }
            acc[nt][i] = v;
        }
    }

    float s[4] = {0.f, 0.f, 0.f, 0.f}, qs[4] = {0.f, 0.f, 0.f, 0.f};
#pragma unroll
    for (int nt = 0; nt < 8; ++nt)
#pragma unroll
        for (int i = 0; i < 4; ++i) {
            float v = acc[nt][i];
            s[i] += v;
            qs[i] += v * v;
        }
#pragma unroll
    for (int i = 0; i < 4; ++i)
#pragma unroll
        for (int o = 1; o < 16; o <<= 1) {
            s[i] += __shfl_xor(s[i], o);
            qs[i] += __shfl_xor(qs[i], o);
        }
    float mu[4], rstd[4];
#pragma unroll
    for (int i = 0; i < 4; ++i) {
        mu[i] = s[i] * (1.f / 128.f);
        float var = qs[i] * (1.f / 128.f) - mu[i] * mu[i];
        rstd[i] = rsqrtf(var + 1e-5f);
    }

#pragma unroll
    for (int nt = 0; nt < 8; ++nt) {
        int col = nt * 16 + cb;
        float gv = g[col], bv = beta[col];
#pragma unroll
        for (int i = 0; i < 4; ++i) {
            int row = m0 + rq + i;
            if (row >= M) continue;
            float y = (acc[nt][i] - mu[i]) * rstd[i] * gv + bv;
            size_t idx = (size_t)row * 128 + col;
            hout[idx] = y;
            hbf[idx] = (__bf16)y;
        }
    }
}

// ------------------------- attention (pipelined gathers) --------------------

__global__ __launch_bounds__(256) void attn_gat(const __bf16* __restrict__ qkv,
                                                const int* __restrict__ row_ptr,
                                                const int* __restrict__ csr_src,
                                                __bf16* __restrict__ agg, int N) {
    int wave = threadIdx.x >> 6;
    int lane = threadIdx.x & 63;
    int n = blockIdx.x * 4 + wave;
    if (n >= N) return;
    int j = lane >> 4, q16 = lane & 15, c0 = q16 * 8;
    const float scale = 0.25f;  // 1/sqrt(16)

    int e0 = row_ptr[n], e1 = row_ptr[n + 1];

    bf16x8 qv = *(const bf16x8*)&qkv[(size_t)n * 384 + c0];
    float qf[8];
#pragma unroll
    for (int i = 0; i < 8; ++i) qf[i] = (float)qv[i];

    float m = -3e38f, s = 0.f;
    float acc[8] = {0.f, 0.f, 0.f, 0.f, 0.f, 0.f, 0.f, 0.f};

    if (e0 < e1) {
        int e = e0 + j;
        bool v0 = e < e1;
        int i0 = csr_src[v0 ? e : e0];
        const __bf16* kp0 = &qkv[(size_t)i0 * 384 + 128 + c0];
        bf16x8 k0 = *(const bf16x8*)kp0;
        bf16x8 vv0 = *(const bf16x8*)(kp0 + 128);
        int en = e0 + 4 + j;
        bool v1 = en < e1;
        int i1 = csr_src[v1 ? en : e0];

        for (int base = e0; base < e1; base += 4) {
            bf16x8 k1, vv1;
            if (base + 4 < e1) {
                const __bf16* kp1 = &qkv[(size_t)i1 * 384 + 128 + c0];
                k1 = *(const bf16x8*)kp1;
                vv1 = *(const bf16x8*)(kp1 + 128);
            }
            int e2 = base + 8 + j;
            bool v2 = e2 < e1;
            int i2 = csr_src[v2 ? e2 : e0];

            float d = 0.f;
#pragma unroll
            for (int i = 0; i < 8; ++i) d = fmaf(qf[i], (float)k0[i], d);
            d += __shfl_xor(d, 1);
            float sc = d * scale;
            if (v0) {
                float mn = fmaxf(m, sc);
                float f = __expf(m - mn), p = __expf(sc - mn);
                s = s * f + p;
#pragma unroll
                for (int i = 0; i < 8; ++i) acc[i] = acc[i] * f + p * (float)vv0[i];
                m = mn;
            }
            k0 = k1; vv0 = vv1; v0 = v1;
            i1 = i2; v1 = v2;
        }
    }

#pragma unroll
    for (int off = 16; off <= 32; off <<= 1) {
        float mo_ = __shfl_xor(m, off);
        float so_ = __shfl_xor(s, off);
        float mn = fmaxf(m, mo_);
        float f = __expf(m - mn), fo = __expf(mo_ - mn);
        s = s * f + so_ * fo;
#pragma unroll
        for (int i = 0; i < 8; ++i)
            acc[i] = acc[i] * f + __shfl_xor(acc[i], off) * fo;
        m = mn;
    }

    if (j == 0) {
        float inv = (s > 0.f) ? 1.f / s : 0.f;
        bf16x8 o;
#pragma unroll
        for (int i = 0; i < 8; ++i) o[i] = (__bf16)(acc[i] * inv);
        *(bf16x8*)&agg[(size_t)n * 128 + c0] = o;
    }
}

// ------------------------- FFN head -----------------------------------------

__global__ __launch_bounds__(512) void ffn_mfma(const __bf16* __restrict__ hbf,
                                                const __bf16* __restrict__ f1P,
                                                const float* __restrict__ f1b,
                                                const __bf16* __restrict__ f2P,
                                                const float* __restrict__ f2b,
                                                const __bf16* __restrict__ f3P,
                                                const float* __restrict__ f3b,
                                                float* __restrict__ out, int M) {
    __shared__ __bf16 hbuf[64 * 512];  // 64 KB; byte = rl*1024+col*2 ^((rl&7)<<4)
    int w = threadIdx.x >> 6;
    int lane = threadIdx.x & 63;
    int r0 = blockIdx.x * 64;
    int cb = lane & 15;
    int kc = (lane >> 4) * 8;
    int rq = (lane >> 4) * 4;
    char* hb = (char*)hbuf;

    // ---- phase 1: h1 = relu(h @ f1w + b1); NT=4, MT=4, K=128 (NKS=4)
    {
        bf16x8 a1[4][4];
#pragma unroll
        for (int mt = 0; mt < 4; ++mt) {
            int row = r0 + mt * 16 + cb;
            if (row >= M) row = M - 1;
#pragma unroll
            for (int ks = 0; ks < 4; ++ks)
                a1[mt][ks] = *(const bf16x8*)&hbf[(size_t)row * 128 + ks * 32 + kc];
        }
        const __bf16* b1p = f1P + (size_t)(w * 4) * 4 * 512 + lane * 8;
        bf16x8 bA[4], bB[4];
#pragma unroll
        for (int ks = 0; ks < 4; ++ks) bA[ks] = *(const bf16x8*)(b1p + ks * 512);
#pragma unroll
        for (int nt = 0; nt < 4; nt += 2) {
#pragma unroll
            for (int ks = 0; ks < 4; ++ks)
                bB[ks] = *(const bf16x8*)(b1p + ((nt + 1) * 4 + ks) * 512);
            {
                f32x4 acc[4];
#pragma unroll
                for (int mt = 0; mt < 4; ++mt) acc[mt] = (f32x4){0.f, 0.f, 0.f, 0.f};
                __builtin_amdgcn_s_setprio(1);
#pragma unroll
                for (int ks = 0; ks < 4; ++ks)
#pragma unroll
                    for (int mt = 0; mt < 4; ++mt)
                        acc[mt] = MFMA16(a1[mt][ks], bA[ks], acc[mt]);
                __builtin_amdgcn_s_setprio(0);
                int ncol = w * 64 + nt * 16;
                float bb = f1b[ncol + cb];
#pragma unroll
                for (int mt = 0; mt < 4; ++mt)
#pragma unroll
                    for (int i = 0; i < 4; ++i) {
                        int rl = mt * 16 + rq + i;
                        int byte = (rl * 1024 + (ncol + cb) * 2) ^ ((rl & 7) << 4);
                        *(__bf16*)(hb + byte) = (__bf16)fmaxf(acc[mt][i] + bb, 0.f);
                    }
            }
            if (nt + 2 < 4) {
#pragma unroll
                for (int ks = 0; ks < 4; ++ks)
                    bA[ks] = *(const bf16x8*)(b1p + ((nt + 2) * 4 + ks) * 512);
            }
            {
                f32x4 acc[4];
#pragma unroll
                for (int mt = 0; mt < 4; ++mt) acc[mt] = (f32x4){0.f, 0.f, 0.f, 0.f};
                __builtin_amdgcn_s_setprio(1);
#pragma unroll
                for (int ks = 0; ks < 4; ++ks)
#pragma unroll
                    for (int mt = 0; mt < 4; ++mt)
                        acc[mt] = MFMA16(a1[mt][ks], bB[ks], acc[mt]);
                __builtin_amdgcn_s_setprio(0);
                int ncol = w * 64 + (nt + 1) * 16;
                float bb = f1b[ncol + cb];
#pragma unroll
                for (int mt = 0; mt < 4; ++mt)
#pragma unroll
                    for (int i = 0; i < 4; ++i) {
                        int rl = mt * 16 + rq + i;
                        int byte = (rl * 1024 + (ncol + cb) * 2) ^ ((rl & 7) << 4);
                        *(__bf16*)(hb + byte) = (__bf16)fmaxf(acc[mt][i] + bb, 0.f);
                    }
            }
        }
    }
    __syncthreads();

    // ---- phase 2: h2 = relu(h1 @ f2w + b2); K=512 (NKS=16)
    {
        f32x4 acc2[4][4];
#pragma unroll
        for (int mt = 0; mt < 4; ++mt)
#pragma unroll
            for (int nt = 0; nt < 4; ++nt) acc2[mt][nt] = (f32x4){0.f, 0.f, 0.f, 0.f};

        const __bf16* b2p = f2P + (size_t)(w * 4) * 16 * 512 + lane * 8;

        bf16x8 b0[4], b1[4];
#pragma unroll
        for (int nt = 0; nt < 4; ++nt) b0[nt] = *(const bf16x8*)(b2p + nt * 16 * 512);

#pragma unroll
        for (int ks = 0; ks < 16; ks += 2) {
#pragma unroll
            for (int nt = 0; nt < 4; ++nt)
                b1[nt] = *(const bf16x8*)(b2p + (nt * 16 + ks + 1) * 512);
            {
                bf16x8 a2[4];
#pragma unroll
                for (int mt = 0; mt < 4; ++mt) {
                    int rl = mt * 16 + cb;
                    int byte = (rl * 1024 + (ks * 32 + kc) * 2) ^ ((rl & 7) << 4);
                    a2[mt] = *(const bf16x8*)(hb + byte);
                }
                __builtin_amdgcn_s_setprio(1);
#pragma unroll
                for (int nt = 0; nt < 4; ++nt)
#pragma unroll
                    for (int mt = 0; mt < 4; ++mt)
                        acc2[mt][nt] = MFMA16(a2[mt], b0[nt], acc2[mt][nt]);
                __builtin_amdgcn_s_setprio(0);
            }
            if (ks + 2 < 16) {
#pragma unroll
                for (int nt = 0; nt < 4; ++nt)
                    b0[nt] = *(const bf16x8*)(b2p + (nt * 16 + ks + 2) * 512);
            }
            {
                bf16x8 a2[4];
#pragma unroll
                for (int mt = 0; mt < 4; ++mt) {
                    int rl = mt * 16 + cb;
                    int byte = (rl * 1024 + ((ks + 1) * 32 + kc) * 2) ^ ((rl & 7) << 4);
                    a2[mt] = *(const bf16x8*)(hb + byte);
                }
                __builtin_amdgcn_s_setprio(1);
#pragma unroll
                for (int nt = 0; nt < 4; ++nt)
#pragma unroll
                    for (int mt = 0; mt < 4; ++mt)
                        acc2[mt][nt] = MFMA16(a2[mt], b1[nt], acc2[mt][nt]);
                __builtin_amdgcn_s_setprio(0);
            }
        }
        __syncthreads();  // all h1 reads done before overwrite

#pragma unroll
        for (int nt = 0; nt < 4; ++nt) {
            int ncol = w * 64 + nt * 16;
            float bb = f2b[ncol + cb];
#pragma unroll
            for (int mt = 0; mt < 4; ++mt)
#pragma unroll
                for (int i = 0; i < 4; ++i) {
                    int rl = mt * 16 + rq + i;
                    int byte = (rl * 1024 + (ncol + cb) * 2) ^ ((rl & 7) << 4);
                    *(__bf16*)(hb + byte) = (__bf16)fmaxf(acc2[mt][nt][i] + bb, 0.f);
                }
        }
    }
    __syncthreads();

    // ---- phase 3: out = h2 @ f3w + b3; waves 0..3 -> m-tile w, n-tiles 0..2
    if (w < 4) {
        f32x4 acc3[3];
#pragma unroll
        for (int nt = 0; nt < 3; ++nt) acc3[nt] = (f32x4){0.f, 0.f, 0.f, 0.f};
        const __bf16* b3p = f3P + lane * 8;
#pragma unroll
        for (int ks = 0; ks < 16; ++ks) {
            int rl = w * 16 + cb;
            int byte = (rl * 1024 + (ks * 32 + kc) * 2) ^ ((rl & 7) << 4);
            bf16x8 a3 = *(const bf16x8*)(hb + byte);
#pragma unroll
            for (int nt = 0; nt < 3; ++nt) {
                bf16x8 b = *(const bf16x8*)(b3p + (nt * 16 + ks) * 512);
                acc3[nt] = MFMA16(a3, b, acc3[nt]);
            }
        }
#pragma unroll
        for (int nt = 0; nt < 3; ++nt) {
            int col = nt * 16 + cb;
            if (col < 47) {
                float bb = f3b[col];
                int r = r0 + w * 16 + rq;
#pragma unroll
                for (int i = 0; i < 4; ++i)
                    if (r + i < M) out[(size_t)(r + i) * 47 + col] = acc3[nt][i] + bb;
            }
        }
    }
}

// ------------------------- launch -------------------------------------------

extern "C" void kernel_launch(void* const* d_in, const int* in_sizes, int n_in,
                              void* d_out, int out_size, void* d_ws, size_t ws_size,
                              hipStream_t stream) {
    const float* X        = (const float*)d_in[0];
    const int*   ei       = (const int*)d_in[1];
    const float* emb_w    = (const float*)d_in[2];
    const float* emb_b    = (const float*)d_in[3];
    const float* emb_ln_g = (const float*)d_in[4];
    const float* emb_ln_b = (const float*)d_in[5];
    const float* Wq       = (const float*)d_in[6];
    const float* Wk       = (const float*)d_in[7];
    const float* Wv       = (const float*)d_in[8];
    const float* Wo       = (const float*)d_in[9];
    const float* ln_g     = (const float*)d_in[10];
    const float* ln_b     = (const float*)d_in[11];
    const float* f1w      = (const float*)d_in[12];
    const float* f1b      = (const float*)d_in[13];
    const float* f2w      = (const float*)d_in[14];
    const float* f2b      = (const float*)d_in[15];
    const float* f3w      = (const float*)d_in[16];
    const float* f3b      = (const float*)d_in[17];

    const int N = in_sizes[0] / 256;  // 50000
    const int E = in_sizes[1] / 2;    // 640000
    const int NB = (N + 1023) / 1024;

    // ---- workspace layout
    char* p = (char*)d_ws;
    float* h = (float*)p;            p += (size_t)N * 128 * 4;
    __bf16* hbf = (__bf16*)p;        p += (size_t)N * 128 * 2;
    __bf16* qkv = (__bf16*)p;        p += (size_t)N * 384 * 2;
    __bf16* aggb = (__bf16*)p;       p += (size_t)N * 128 * 2;
    __bf16* embT = (__bf16*)p;       p += 128 * 256 * 2;
    __bf16* qkvT = (__bf16*)p;       p += 3 * 384 * 128 * 2;
    __bf16* woT = (__bf16*)p;        p += 3 * 128 * 128 * 2;
    __bf16* f1T = (__bf16*)p;        p += 512 * 128 * 2;
    __bf16* f2T = (__bf16*)p;        p += 512 * 512 * 2;
    __bf16* f3T = (__bf16*)p;        p += 48 * 512 * 2;
    __bf16* f1P = (__bf16*)p;        p += 8192 * 8 * 2;
    __bf16* f2P = (__bf16*)p;        p += 32768 * 8 * 2;
    __bf16* f3P = (__bf16*)p;        p += 3072 * 8 * 2;
    __bf16* embP = (__bf16*)p;       p += 4096 * 8 * 2;
    __bf16* woP = (__bf16*)p;        p += 6144 * 8 * 2;
    int* deg = (int*)p;              p += (size_t)N * 4;
    int* cursor = (int*)p;           p += (size_t)N * 4;
    int* row_ptr = (int*)p;          p += (size_t)(N + 1) * 4;
    int* csr_src = (int*)p;          p += (size_t)E * 4;
    int* partials = (int*)p;

    // ---- CSR build
    hipMemsetAsync(deg, 0, (size_t)2 * N * 4, stream);  // zeros deg + cursor
    count_deg<<<(E + 255) / 256, 256, 0, stream>>>(ei, deg, E);
    scan_part<<<NB, 256, 0, stream>>>(deg, partials, N);
    scan_mid<<<1, 64, 0, stream>>>(partials, row_ptr, NB, N);
    scan_final<<<NB, 256, 0, stream>>>(deg, partials, row_ptr, N);
    scatter_edges<<<(E + 255) / 256, 256, 0, stream>>>(ei, row_ptr, cursor, csr_src, E);

    transpose_all<<<576, 256, 0, stream>>>(emb_w, f1w, f2w, f3w, Wq, Wk, Wv, Wo,
                                           embT, f1T, f2T, f3T, qkvT, woT);
    pack_frag<<<212, 256, 0, stream>>>(f1T, f2T, f3T, embT, woT,
                                       f1P, f2P, f3P, embP, woP);

    int gwave = (N + 15) / 16;    // 3125 one-wave blocks for gemm_ln
    int gm128 = (N + 127) / 128;  // 391 row panels for gemm_tile

    // ---- embedding: LN(relu(X @ emb_w + emb_b)) -> h (fp32) + hbf
    gemm_ln<256, true><<<gwave, 64, 0, stream>>>(X, embP, emb_b, nullptr,
                                                 emb_ln_g, emb_ln_b, h, hbf, N);

    // ---- layers
    for (int l = 0; l < 3; ++l) {
        gemm_tile<4, 0><<<dim3(3, gm128), 256, 0, stream>>>(
            hbf, qkvT + (size_t)l * 49152, nullptr, qkv, N, 384, 384);
        attn_gat<<<(N + 3) / 4, 256, 0, stream>>>(qkv, row_ptr, csr_src, aggb, N);
        gemm_ln<128, false><<<gwave, 64, 0, stream>>>(aggb, woP + (size_t)l * 16384,
                                                      nullptr, h,
                                                      ln_g + (size_t)l * 128,
                                                      ln_b + (size_t)l * 128, h, hbf, N);
    }

    // ---- FFN head
    ffn_mfma<<<(N + 63) / 64, 512, 0, stream>>>(hbf, f1P, f1b, f2P, f2b, f3P, f3b,
                                                (float*)d_out, N);
}